// Round 2
// baseline (3597.984 us; speedup 1.0000x reference)
//
#include <hip/hip_runtime.h>
#include <hip/hip_bf16.h>
#include <math.h>

#define N_NODES 50000
#define NE      800000
#define D       128
#define H       8
#define DH      16
#define NLAYER  2
#define IN_F    128
#define PP      8192
#define FF      256

static __device__ __forceinline__ void atomicMaxF(float* addr, float val) {
    unsigned int uv = __float_as_uint(val);
    if (!(uv >> 31)) {
        atomicMax((int*)addr, (int)uv);          // non-negative: int order == float order
    } else {
        atomicMin((unsigned int*)addr, uv);      // negative: uint order is reversed float order
    }
}

__global__ void fill_kernel(float* __restrict__ p, float v, int n) {
    int i = blockIdx.x * blockDim.x + threadIdx.x;
    if (i < n) p[i] = v;
}

// C[M,Nc] = act(A[M,K] @ W[K,Nc] + bias[Nc]); act: 0=none, 1=relu
__global__ __launch_bounds__(256) void gemm_bias(
    const float* __restrict__ A, const float* __restrict__ W,
    const float* __restrict__ bias, float* __restrict__ C,
    int M, int K, int Nc, int act)
{
    __shared__ float As[16][64];
    __shared__ float Bs[16][64];
    const int r0 = blockIdx.x * 64, c0 = blockIdx.y * 64;
    const int t = threadIdx.x;
    const int tm = t >> 4, tn = t & 15;
    const int lm = t >> 2, lk0 = (t & 3) * 4;   // A-tile load coords
    const int wk = t >> 4, wn0 = (t & 15) * 4;  // W-tile load coords
    float acc[4][4] = {};

    for (int k0 = 0; k0 < K; k0 += 16) {
        float4 a4 = make_float4(0.f, 0.f, 0.f, 0.f);
        if (r0 + lm < M)
            a4 = *(const float4*)(A + (size_t)(r0 + lm) * K + k0 + lk0);
        float4 w4 = *(const float4*)(W + (size_t)(k0 + wk) * Nc + c0 + wn0);
        __syncthreads();
        As[lk0 + 0][lm] = a4.x; As[lk0 + 1][lm] = a4.y;
        As[lk0 + 2][lm] = a4.z; As[lk0 + 3][lm] = a4.w;
        *(float4*)&Bs[wk][wn0] = w4;
        __syncthreads();
        #pragma unroll
        for (int kk = 0; kk < 16; kk++) {
            float4 av = *(const float4*)&As[kk][tm * 4];
            float4 bv = *(const float4*)&Bs[kk][tn * 4];
            float aa[4] = {av.x, av.y, av.z, av.w};
            float bb[4] = {bv.x, bv.y, bv.z, bv.w};
            #pragma unroll
            for (int i = 0; i < 4; i++)
                #pragma unroll
                for (int j = 0; j < 4; j++)
                    acc[i][j] += aa[i] * bb[j];
        }
    }
    #pragma unroll
    for (int i = 0; i < 4; i++) {
        int r = r0 + tm * 4 + i;
        if (r >= M) continue;
        #pragma unroll
        for (int j = 0; j < 4; j++) {
            int c = c0 + tn * 4 + j;
            float v = acc[i][j] + bias[c];
            if (act == 1) v = fmaxf(v, 0.f);
            C[(size_t)r * Nc + c] = v;
        }
    }
}

// per (edge, head): sc = scale * dot(q[dst,h,:], k[src,h,:]); atomic segment-max into m
__global__ void score_kernel(const float* __restrict__ q, const float* __restrict__ k,
                             const int* __restrict__ src, const int* __restrict__ dst,
                             float* __restrict__ sc, float* __restrict__ m)
{
    int id = blockIdx.x * blockDim.x + threadIdx.x;
    if (id >= NE * H) return;
    int e = id >> 3, hh = id & 7;
    int s = src[e], d = dst[e];
    const float4* qp = (const float4*)(q + (size_t)d * D + hh * DH);
    const float4* kp = (const float4*)(k + (size_t)s * D + hh * DH);
    float acc = 0.f;
    #pragma unroll
    for (int j = 0; j < 4; j++) {
        float4 a = qp[j], b = kp[j];
        acc += a.x * b.x + a.y * b.y + a.z * b.z + a.w * b.w;
    }
    acc *= 0.25f;   // 1/sqrt(DH)
    sc[id] = acc;
    atomicMaxF(m + (size_t)d * H + hh, acc);
}

// per (edge, head): ex = exp(sc - m[dst]); store over sc; atomic segment-sum into den
__global__ void ex_kernel(float* __restrict__ sc, const float* __restrict__ m,
                          float* __restrict__ den, const int* __restrict__ dst)
{
    int id = blockIdx.x * blockDim.x + threadIdx.x;
    if (id >= NE * H) return;
    int e = id >> 3, hh = id & 7;
    int d = dst[e];
    float v = expf(sc[id] - m[(size_t)d * H + hh]);
    sc[id] = v;
    atomicAdd(den + (size_t)d * H + hh, v);
}

// per (edge, 4-float chunk): agg[dst] += alpha * v[src]
__global__ void agg_kernel(const float* __restrict__ ex, const float* __restrict__ den,
                           const float* __restrict__ v, const int* __restrict__ src,
                           const int* __restrict__ dst, float* __restrict__ agg)
{
    long long id = (long long)blockIdx.x * blockDim.x + threadIdx.x;
    if (id >= (long long)NE * 32) return;
    int e = (int)(id >> 5), c = (int)(id & 31);
    int d0 = c * 4, hh = d0 >> 4;
    int s = src[e], dd = dst[e];
    float alpha = ex[(size_t)e * H + hh] / (den[(size_t)dd * H + hh] + 1e-9f);
    float4 vv = *(const float4*)(v + (size_t)s * D + d0);
    float* ap = agg + (size_t)dd * D + d0;
    atomicAdd(ap + 0, alpha * vv.x);
    atomicAdd(ap + 1, alpha * vv.y);
    atomicAdd(ap + 2, alpha * vv.z);
    atomicAdd(ap + 3, alpha * vv.w);
}

// out = LN(a + b) * g + be ; one wave per row (D=128, 2 elems/lane); out may alias a
__global__ void ln_fused(const float* __restrict__ a, const float* __restrict__ b,
                         const float* __restrict__ g, const float* __restrict__ be,
                         float* __restrict__ out, int M)
{
    int wid = threadIdx.x >> 6, lane = threadIdx.x & 63;
    int row = blockIdx.x * 4 + wid;
    if (row >= M) return;
    const float* ar = a + (size_t)row * D;
    const float* br = b + (size_t)row * D;
    float x1 = ar[lane] + br[lane];
    float x2 = ar[lane + 64] + br[lane + 64];
    float s = x1 + x2;
    #pragma unroll
    for (int o = 32; o > 0; o >>= 1) s += __shfl_xor(s, o);
    float mean = s * (1.f / 128.f);
    float d1 = x1 - mean, d2 = x2 - mean;
    float vs = d1 * d1 + d2 * d2;
    #pragma unroll
    for (int o = 32; o > 0; o >>= 1) vs += __shfl_xor(vs, o);
    float rstd = rsqrtf(vs * (1.f / 128.f) + 1e-5f);
    float* orow = out + (size_t)row * D;
    orow[lane]      = d1 * rstd * g[lane]      + be[lane];
    orow[lane + 64] = d2 * rstd * g[lane + 64] + be[lane + 64];
}

// one 64-thread block per pair: score = leaky_relu((h[a]*h[b]) @ Wp1 + bp1) @ Wp2 + bp2
__global__ void predict_kernel(const float* __restrict__ h,
                               const int* __restrict__ ai, const int* __restrict__ bi,
                               const float* __restrict__ Wp1, const float* __restrict__ bp1,
                               const float* __restrict__ Wp2, const float* __restrict__ bp2,
                               float* __restrict__ out)
{
    __shared__ float z[128];
    int p = blockIdx.x;
    int a = ai[p], b = bi[p];
    int t = threadIdx.x;
    z[t]      = h[(size_t)a * D + t]      * h[(size_t)b * D + t];
    z[t + 64] = h[(size_t)a * D + t + 64] * h[(size_t)b * D + t + 64];
    __syncthreads();
    float acc = bp1[t];
    #pragma unroll 4
    for (int i = 0; i < 128; i++) acc += z[i] * Wp1[(size_t)i * 64 + t];
    acc = acc > 0.f ? acc : 0.2f * acc;
    float part = acc * Wp2[t];
    #pragma unroll
    for (int o = 32; o > 0; o >>= 1) part += __shfl_down(part, o);
    if (t == 0) out[p] = part + bp2[0];
}

extern "C" void kernel_launch(void* const* d_in, const int* in_sizes, int n_in,
                              void* d_out, int out_size, void* d_ws, size_t ws_size,
                              hipStream_t stream)
{
    const float* x       = (const float*)d_in[0];
    const int*   src     = (const int*)d_in[1];
    const int*   dst     = (const int*)d_in[2];
    const int*   pos_src = (const int*)d_in[3];
    const int*   pos_dst = (const int*)d_in[4];
    const int*   neg_src = (const int*)d_in[5];
    const int*   neg_dst = (const int*)d_in[6];
    const float* W_in = (const float*)d_in[7];
    const float* b_in = (const float*)d_in[8];
    const float* Wq = (const float*)d_in[9];
    const float* bq = (const float*)d_in[10];
    const float* Wk = (const float*)d_in[11];
    const float* bk = (const float*)d_in[12];
    const float* Wv = (const float*)d_in[13];
    const float* bv = (const float*)d_in[14];
    const float* Wo = (const float*)d_in[15];
    const float* bo = (const float*)d_in[16];
    const float* ln1g = (const float*)d_in[17];
    const float* ln1b = (const float*)d_in[18];
    const float* Wf1 = (const float*)d_in[19];
    const float* bf1 = (const float*)d_in[20];
    const float* Wf2 = (const float*)d_in[21];
    const float* bf2 = (const float*)d_in[22];
    const float* ln2g = (const float*)d_in[23];
    const float* ln2b = (const float*)d_in[24];
    const float* Wp1 = (const float*)d_in[25];
    const float* bp1 = (const float*)d_in[26];
    const float* Wp2 = (const float*)d_in[27];
    const float* bp2 = (const float*)d_in[28];

    float* out = (float*)d_out;
    float* h   = out + 2 * PP;          // h lives directly in d_out

    const size_t S = (size_t)N_NODES * D;   // 6.4M floats
    float* ws   = (float*)d_ws;
    float* q    = ws;                   // [N,D]; reused as agg, then as FFN-hidden (with k)
    float* kbuf = ws + S;               // [N,D]
    float* vbuf = ws + 2 * S;           // [N,D]
    float* sc   = ws + 3 * S;           // [E,H] scores/ex; reused as GEMM tmp
    float* mbuf = ws + 4 * S;           // [N,H]
    float* den  = mbuf + (size_t)N_NODES * H;
    float* ff   = ws;                   // [N,FF] spans q+kbuf slots
    float* tmp  = sc;                   // [N,D] GEMM output tmp (after ex consumed)

    auto cdiv = [](int a, int b) { return (a + b - 1) / b; };
    const int gM = cdiv(N_NODES, 64);

    // h = x @ W_in + b_in
    gemm_bias<<<dim3(gM, D / 64), 256, 0, stream>>>(x, W_in, b_in, h, N_NODES, IN_F, D, 0);

    for (int l = 0; l < NLAYER; l++) {
        const int* sl = src + (size_t)l * NE;
        const int* dl = dst + (size_t)l * NE;

        gemm_bias<<<dim3(gM, D / 64), 256, 0, stream>>>(h, Wq + (size_t)l * D * D, bq + l * D, q,    N_NODES, D, D, 0);
        gemm_bias<<<dim3(gM, D / 64), 256, 0, stream>>>(h, Wk + (size_t)l * D * D, bk + l * D, kbuf, N_NODES, D, D, 0);
        gemm_bias<<<dim3(gM, D / 64), 256, 0, stream>>>(h, Wv + (size_t)l * D * D, bv + l * D, vbuf, N_NODES, D, D, 0);

        fill_kernel<<<cdiv(N_NODES * H, 256), 256, 0, stream>>>(mbuf, -INFINITY, N_NODES * H);
        fill_kernel<<<cdiv(N_NODES * H, 256), 256, 0, stream>>>(den, 0.f, N_NODES * H);

        score_kernel<<<cdiv(NE * H, 256), 256, 0, stream>>>(q, kbuf, sl, dl, sc, mbuf);
        ex_kernel<<<cdiv(NE * H, 256), 256, 0, stream>>>(sc, mbuf, den, dl);

        // agg into q slot (q no longer needed)
        fill_kernel<<<cdiv((int)S, 256), 256, 0, stream>>>(q, 0.f, (int)S);
        agg_kernel<<<cdiv(NE * 32, 256), 256, 0, stream>>>(sc, den, vbuf, sl, dl, q);

        // attn out = agg @ Wo + bo -> tmp ; h = LN(h + tmp)
        gemm_bias<<<dim3(gM, D / 64), 256, 0, stream>>>(q, Wo + (size_t)l * D * D, bo + l * D, tmp, N_NODES, D, D, 0);
        ln_fused<<<cdiv(N_NODES, 4), 256, 0, stream>>>(h, tmp, ln1g + l * D, ln1b + l * D, h, N_NODES);

        // FFN
        gemm_bias<<<dim3(gM, FF / 64), 256, 0, stream>>>(h, Wf1 + (size_t)l * D * FF, bf1 + l * FF, ff, N_NODES, D, FF, 1);
        gemm_bias<<<dim3(gM, D / 64), 256, 0, stream>>>(ff, Wf2 + (size_t)l * FF * D, bf2 + l * D, tmp, N_NODES, FF, D, 0);
        ln_fused<<<cdiv(N_NODES, 4), 256, 0, stream>>>(h, tmp, ln2g + l * D, ln2b + l * D, h, N_NODES);
    }

    predict_kernel<<<PP, 64, 0, stream>>>(h, pos_src, pos_dst, Wp1, bp1, Wp2, bp2, out);
    predict_kernel<<<PP, 64, 0, stream>>>(h, neg_src, neg_dst, Wp1, bp1, Wp2, bp2, out + PP);
}

// Round 3
// 1274.457 us; speedup vs baseline: 2.8232x; 2.8232x over previous
//
#include <hip/hip_runtime.h>
#include <hip/hip_bf16.h>
#include <math.h>

#define N_NODES 50000
#define NE      800000
#define D       128
#define H       8
#define DH      16
#define NLAYER  2
#define IN_F    128
#define PP      8192
#define FF      256

__global__ void fill_int(int* __restrict__ p, int v, int n) {
    int i = blockIdx.x * blockDim.x + threadIdx.x;
    if (i < n) p[i] = v;
}

__global__ void count_kernel(const int* __restrict__ dst, int* __restrict__ cnt) {
    int e = blockIdx.x * blockDim.x + threadIdx.x;
    if (e < NE) atomicAdd(&cnt[dst[e]], 1);
}

// exclusive scan of cnt[0..N) into ptr[0..N], single block of 1024
__global__ __launch_bounds__(1024) void scan_kernel(const int* __restrict__ cnt, int* __restrict__ ptr) {
    __shared__ int sdata[1024];
    __shared__ int soff;
    if (threadIdx.x == 0) soff = 0;
    __syncthreads();
    for (int base = 0; base < N_NODES; base += 1024) {
        int i = base + threadIdx.x;
        int v = (i < N_NODES) ? cnt[i] : 0;
        sdata[threadIdx.x] = v;
        __syncthreads();
        #pragma unroll
        for (int o = 1; o < 1024; o <<= 1) {
            int t = (threadIdx.x >= o) ? sdata[threadIdx.x - o] : 0;
            __syncthreads();
            sdata[threadIdx.x] += t;
            __syncthreads();
        }
        if (i < N_NODES) ptr[i] = soff + sdata[threadIdx.x] - v;
        __syncthreads();
        if (threadIdx.x == 1023) soff += sdata[1023];
        __syncthreads();
    }
    if (threadIdx.x == 0) ptr[N_NODES] = soff;
}

__global__ void scatter_kernel(const int* __restrict__ dst, const int* __restrict__ ptr,
                               int* __restrict__ cnt, int* __restrict__ eid) {
    int e = blockIdx.x * blockDim.x + threadIdx.x;
    if (e < NE) {
        int d = dst[e];
        int pos = ptr[d] + atomicAdd(&cnt[d], 1);
        eid[pos] = e;
    }
}

// C[M,Nc] = act(A[M,K] @ W[K,Nc] + bias[Nc]); act: 0=none, 1=relu
__global__ __launch_bounds__(256) void gemm_bias(
    const float* __restrict__ A, const float* __restrict__ W,
    const float* __restrict__ bias, float* __restrict__ C,
    int M, int K, int Nc, int act)
{
    __shared__ float As[16][64];
    __shared__ float Bs[16][64];
    const int r0 = blockIdx.x * 64, c0 = blockIdx.y * 64;
    const int t = threadIdx.x;
    const int tm = t >> 4, tn = t & 15;
    const int lm = t >> 2, lk0 = (t & 3) * 4;
    const int wk = t >> 4, wn0 = (t & 15) * 4;
    float acc[4][4] = {};

    for (int k0 = 0; k0 < K; k0 += 16) {
        float4 a4 = make_float4(0.f, 0.f, 0.f, 0.f);
        if (r0 + lm < M)
            a4 = *(const float4*)(A + (size_t)(r0 + lm) * K + k0 + lk0);
        float4 w4 = *(const float4*)(W + (size_t)(k0 + wk) * Nc + c0 + wn0);
        __syncthreads();
        As[lk0 + 0][lm] = a4.x; As[lk0 + 1][lm] = a4.y;
        As[lk0 + 2][lm] = a4.z; As[lk0 + 3][lm] = a4.w;
        *(float4*)&Bs[wk][wn0] = w4;
        __syncthreads();
        #pragma unroll
        for (int kk = 0; kk < 16; kk++) {
            float4 av = *(const float4*)&As[kk][tm * 4];
            float4 bv = *(const float4*)&Bs[kk][tn * 4];
            float aa[4] = {av.x, av.y, av.z, av.w};
            float bb[4] = {bv.x, bv.y, bv.z, bv.w};
            #pragma unroll
            for (int i = 0; i < 4; i++)
                #pragma unroll
                for (int j = 0; j < 4; j++)
                    acc[i][j] += aa[i] * bb[j];
        }
    }
    #pragma unroll
    for (int i = 0; i < 4; i++) {
        int r = r0 + tm * 4 + i;
        if (r >= M) continue;
        #pragma unroll
        for (int j = 0; j < 4; j++) {
            int c = c0 + tn * 4 + j;
            float v = acc[i][j] + bias[c];
            if (act == 1) v = fmaxf(v, 0.f);
            C[(size_t)r * Nc + c] = v;
        }
    }
}

// Fused attention: one thread per (dst node, head). Two passes over the node's
// incoming edge list (CSR): pass1 max of q.k, pass2 exp/sum/weighted-v.
// Writes normalized aggregate in-place over q (each thread owns its slice).
__global__ __launch_bounds__(256) void attn_fused(
    const float* __restrict__ q, const float* __restrict__ k, const float* __restrict__ v,
    const int* __restrict__ src, const int* __restrict__ ptr, const int* __restrict__ eid,
    float* __restrict__ aggout)
{
    int tid = blockIdx.x * blockDim.x + threadIdx.x;
    if (tid >= N_NODES * H) return;
    int d = tid >> 3, hh = tid & 7;
    const float* qp = q + (size_t)d * D + hh * DH;
    float4 q0 = *(const float4*)(qp + 0);
    float4 q1 = *(const float4*)(qp + 4);
    float4 q2 = *(const float4*)(qp + 8);
    float4 q3 = *(const float4*)(qp + 12);
    int beg = ptr[d], end = ptr[d + 1];

    float mx = -INFINITY;
    for (int i = beg; i < end; i++) {
        int s = src[eid[i]];
        const float* kp = k + (size_t)s * D + hh * DH;
        float4 k0 = *(const float4*)(kp + 0);
        float4 k1 = *(const float4*)(kp + 4);
        float4 k2 = *(const float4*)(kp + 8);
        float4 k3 = *(const float4*)(kp + 12);
        float dot = q0.x*k0.x + q0.y*k0.y + q0.z*k0.z + q0.w*k0.w
                  + q1.x*k1.x + q1.y*k1.y + q1.z*k1.z + q1.w*k1.w
                  + q2.x*k2.x + q2.y*k2.y + q2.z*k2.z + q2.w*k2.w
                  + q3.x*k3.x + q3.y*k3.y + q3.z*k3.z + q3.w*k3.w;
        mx = fmaxf(mx, dot);
    }

    float den = 0.f;
    float4 a0 = {0,0,0,0}, a1 = {0,0,0,0}, a2 = {0,0,0,0}, a3 = {0,0,0,0};
    for (int i = beg; i < end; i++) {
        int s = src[eid[i]];
        const float* kp = k + (size_t)s * D + hh * DH;
        float4 k0 = *(const float4*)(kp + 0);
        float4 k1 = *(const float4*)(kp + 4);
        float4 k2 = *(const float4*)(kp + 8);
        float4 k3 = *(const float4*)(kp + 12);
        float dot = q0.x*k0.x + q0.y*k0.y + q0.z*k0.z + q0.w*k0.w
                  + q1.x*k1.x + q1.y*k1.y + q1.z*k1.z + q1.w*k1.w
                  + q2.x*k2.x + q2.y*k2.y + q2.z*k2.z + q2.w*k2.w
                  + q3.x*k3.x + q3.y*k3.y + q3.z*k3.z + q3.w*k3.w;
        float w = __expf((dot - mx) * 0.25f);   // scale = 1/sqrt(16)
        den += w;
        const float* vp = v + (size_t)s * D + hh * DH;
        float4 v0 = *(const float4*)(vp + 0);
        float4 v1 = *(const float4*)(vp + 4);
        float4 v2 = *(const float4*)(vp + 8);
        float4 v3 = *(const float4*)(vp + 12);
        a0.x += w*v0.x; a0.y += w*v0.y; a0.z += w*v0.z; a0.w += w*v0.w;
        a1.x += w*v1.x; a1.y += w*v1.y; a1.z += w*v1.z; a1.w += w*v1.w;
        a2.x += w*v2.x; a2.y += w*v2.y; a2.z += w*v2.z; a2.w += w*v2.w;
        a3.x += w*v3.x; a3.y += w*v3.y; a3.z += w*v3.z; a3.w += w*v3.w;
    }
    float r = 1.f / (den + 1e-9f);
    float* op = aggout + (size_t)d * D + hh * DH;
    a0.x *= r; a0.y *= r; a0.z *= r; a0.w *= r;
    a1.x *= r; a1.y *= r; a1.z *= r; a1.w *= r;
    a2.x *= r; a2.y *= r; a2.z *= r; a2.w *= r;
    a3.x *= r; a3.y *= r; a3.z *= r; a3.w *= r;
    *(float4*)(op + 0)  = a0;
    *(float4*)(op + 4)  = a1;
    *(float4*)(op + 8)  = a2;
    *(float4*)(op + 12) = a3;
}

// out = LN(a + b) * g + be ; one wave per row; out may alias a
__global__ void ln_fused(const float* __restrict__ a, const float* __restrict__ b,
                         const float* __restrict__ g, const float* __restrict__ be,
                         float* __restrict__ out, int M)
{
    int wid = threadIdx.x >> 6, lane = threadIdx.x & 63;
    int row = blockIdx.x * 4 + wid;
    if (row >= M) return;
    const float* ar = a + (size_t)row * D;
    const float* br = b + (size_t)row * D;
    float x1 = ar[lane] + br[lane];
    float x2 = ar[lane + 64] + br[lane + 64];
    float s = x1 + x2;
    #pragma unroll
    for (int o = 32; o > 0; o >>= 1) s += __shfl_xor(s, o);
    float mean = s * (1.f / 128.f);
    float d1 = x1 - mean, d2 = x2 - mean;
    float vs = d1 * d1 + d2 * d2;
    #pragma unroll
    for (int o = 32; o > 0; o >>= 1) vs += __shfl_xor(vs, o);
    float rstd = rsqrtf(vs * (1.f / 128.f) + 1e-5f);
    float* orow = out + (size_t)row * D;
    orow[lane]      = d1 * rstd * g[lane]      + be[lane];
    orow[lane + 64] = d2 * rstd * g[lane + 64] + be[lane + 64];
}

__global__ void predict_kernel(const float* __restrict__ h,
                               const int* __restrict__ ai, const int* __restrict__ bi,
                               const float* __restrict__ Wp1, const float* __restrict__ bp1,
                               const float* __restrict__ Wp2, const float* __restrict__ bp2,
                               float* __restrict__ out)
{
    __shared__ float z[128];
    int p = blockIdx.x;
    int a = ai[p], b = bi[p];
    int t = threadIdx.x;
    z[t]      = h[(size_t)a * D + t]      * h[(size_t)b * D + t];
    z[t + 64] = h[(size_t)a * D + t + 64] * h[(size_t)b * D + t + 64];
    __syncthreads();
    float acc = bp1[t];
    #pragma unroll 4
    for (int i = 0; i < 128; i++) acc += z[i] * Wp1[(size_t)i * 64 + t];
    acc = acc > 0.f ? acc : 0.2f * acc;
    float part = acc * Wp2[t];
    #pragma unroll
    for (int o = 32; o > 0; o >>= 1) part += __shfl_down(part, o);
    if (t == 0) out[p] = part + bp2[0];
}

extern "C" void kernel_launch(void* const* d_in, const int* in_sizes, int n_in,
                              void* d_out, int out_size, void* d_ws, size_t ws_size,
                              hipStream_t stream)
{
    const float* x       = (const float*)d_in[0];
    const int*   src     = (const int*)d_in[1];
    const int*   dst     = (const int*)d_in[2];
    const int*   pos_src = (const int*)d_in[3];
    const int*   pos_dst = (const int*)d_in[4];
    const int*   neg_src = (const int*)d_in[5];
    const int*   neg_dst = (const int*)d_in[6];
    const float* W_in = (const float*)d_in[7];
    const float* b_in = (const float*)d_in[8];
    const float* Wq = (const float*)d_in[9];
    const float* bq = (const float*)d_in[10];
    const float* Wk = (const float*)d_in[11];
    const float* bk = (const float*)d_in[12];
    const float* Wv = (const float*)d_in[13];
    const float* bv = (const float*)d_in[14];
    const float* Wo = (const float*)d_in[15];
    const float* bo = (const float*)d_in[16];
    const float* ln1g = (const float*)d_in[17];
    const float* ln1b = (const float*)d_in[18];
    const float* Wf1 = (const float*)d_in[19];
    const float* bf1 = (const float*)d_in[20];
    const float* Wf2 = (const float*)d_in[21];
    const float* bf2 = (const float*)d_in[22];
    const float* ln2g = (const float*)d_in[23];
    const float* ln2b = (const float*)d_in[24];
    const float* Wp1 = (const float*)d_in[25];
    const float* bp1 = (const float*)d_in[26];
    const float* Wp2 = (const float*)d_in[27];
    const float* bp2 = (const float*)d_in[28];

    float* out = (float*)d_out;
    float* h   = out + 2 * PP;              // h lives directly in d_out

    const size_t S = (size_t)N_NODES * D;
    float* ws   = (float*)d_ws;
    float* q    = ws;                        // [N,D] q -> agg (in-place)
    float* kbuf = ws + S;                    // [N,D] k -> tmp1
    float* vbuf = ws + 2 * S;                // [N,D] v -> tmp2
    int*   ptr  = (int*)(ws + 3 * S);        // [N+1]
    int*   cnt  = ptr + (N_NODES + 1);       // [N]
    int*   eid  = cnt + N_NODES;             // [E]
    float* ff   = ws;                        // [N,FF] spans q+k slots (after attn+Wo done)

    auto cdiv = [](int a, int b) { return (a + b - 1) / b; };
    const int gM = cdiv(N_NODES, 64);

    // h = x @ W_in + b_in
    gemm_bias<<<dim3(gM, D / 64), 256, 0, stream>>>(x, W_in, b_in, h, N_NODES, IN_F, D, 0);

    for (int l = 0; l < NLAYER; l++) {
        const int* sl = src + (size_t)l * NE;
        const int* dl = dst + (size_t)l * NE;

        // --- CSR build over dst ---
        fill_int<<<cdiv(N_NODES, 256), 256, 0, stream>>>(cnt, 0, N_NODES);
        count_kernel<<<cdiv(NE, 256), 256, 0, stream>>>(dl, cnt);
        scan_kernel<<<1, 1024, 0, stream>>>(cnt, ptr);
        fill_int<<<cdiv(N_NODES, 256), 256, 0, stream>>>(cnt, 0, N_NODES);
        scatter_kernel<<<cdiv(NE, 256), 256, 0, stream>>>(dl, ptr, cnt, eid);

        // --- projections ---
        gemm_bias<<<dim3(gM, D / 64), 256, 0, stream>>>(h, Wq + (size_t)l * D * D, bq + l * D, q,    N_NODES, D, D, 0);
        gemm_bias<<<dim3(gM, D / 64), 256, 0, stream>>>(h, Wk + (size_t)l * D * D, bk + l * D, kbuf, N_NODES, D, D, 0);
        gemm_bias<<<dim3(gM, D / 64), 256, 0, stream>>>(h, Wv + (size_t)l * D * D, bv + l * D, vbuf, N_NODES, D, D, 0);

        // --- fused attention (agg written in-place over q) ---
        attn_fused<<<cdiv(N_NODES * H, 256), 256, 0, stream>>>(q, kbuf, vbuf, sl, ptr, eid, q);

        // attn out = agg @ Wo + bo -> kbuf ; h = LN(h + kbuf)
        gemm_bias<<<dim3(gM, D / 64), 256, 0, stream>>>(q, Wo + (size_t)l * D * D, bo + l * D, kbuf, N_NODES, D, D, 0);
        ln_fused<<<cdiv(N_NODES, 4), 256, 0, stream>>>(h, kbuf, ln1g + l * D, ln1b + l * D, h, N_NODES);

        // FFN: ff = relu(h @ Wf1 + bf1) ; tmp = ff @ Wf2 + bf2 -> vbuf ; h = LN(h + vbuf)
        gemm_bias<<<dim3(gM, FF / 64), 256, 0, stream>>>(h, Wf1 + (size_t)l * D * FF, bf1 + l * FF, ff, N_NODES, D, FF, 1);
        gemm_bias<<<dim3(gM, D / 64), 256, 0, stream>>>(ff, Wf2 + (size_t)l * FF * D, bf2 + l * D, vbuf, N_NODES, FF, D, 0);
        ln_fused<<<cdiv(N_NODES, 4), 256, 0, stream>>>(h, vbuf, ln2g + l * D, ln2b + l * D, h, N_NODES);
    }

    predict_kernel<<<PP, 64, 0, stream>>>(h, pos_src, pos_dst, Wp1, bp1, Wp2, bp2, out);
    predict_kernel<<<PP, 64, 0, stream>>>(h, neg_src, neg_dst, Wp1, bp1, Wp2, bp2, out + PP);
}

// Round 4
// 1123.444 us; speedup vs baseline: 3.2026x; 1.1344x over previous
//
#include <hip/hip_runtime.h>
#include <hip/hip_bf16.h>
#include <math.h>

#define N_NODES 50000
#define NE      800000
#define D       128
#define H       8
#define DH      16
#define NLAYER  2
#define IN_F    128
#define PP      8192
#define FF      256

__global__ void fill_int(int* __restrict__ p, int v, int n) {
    int i = blockIdx.x * blockDim.x + threadIdx.x;
    if (i < n) p[i] = v;
}

__global__ void count_kernel(const int* __restrict__ dst, int* __restrict__ cnt) {
    int e = blockIdx.x * blockDim.x + threadIdx.x;
    if (e < NE) atomicAdd(&cnt[dst[e]], 1);
}

// exclusive scan of cnt[0..N) into ptr[0..N], single block of 1024
__global__ __launch_bounds__(1024) void scan_kernel(const int* __restrict__ cnt, int* __restrict__ ptr) {
    __shared__ int sdata[1024];
    __shared__ int soff;
    if (threadIdx.x == 0) soff = 0;
    __syncthreads();
    for (int base = 0; base < N_NODES; base += 1024) {
        int i = base + threadIdx.x;
        int v = (i < N_NODES) ? cnt[i] : 0;
        sdata[threadIdx.x] = v;
        __syncthreads();
        #pragma unroll
        for (int o = 1; o < 1024; o <<= 1) {
            int t = (threadIdx.x >= o) ? sdata[threadIdx.x - o] : 0;
            __syncthreads();
            sdata[threadIdx.x] += t;
            __syncthreads();
        }
        if (i < N_NODES) ptr[i] = soff + sdata[threadIdx.x] - v;
        __syncthreads();
        if (threadIdx.x == 1023) soff += sdata[1023];
        __syncthreads();
    }
    if (threadIdx.x == 0) ptr[N_NODES] = soff;
}

// bucket edges by dst; store the SRC node id directly (no eid indirection later)
__global__ void scatter_kernel(const int* __restrict__ dst, const int* __restrict__ src,
                               const int* __restrict__ ptr, int* __restrict__ cnt,
                               int* __restrict__ ssrc) {
    int e = blockIdx.x * blockDim.x + threadIdx.x;
    if (e < NE) {
        int d = dst[e];
        int pos = ptr[d] + atomicAdd(&cnt[d], 1);
        ssrc[pos] = src[e];
    }
}

// C[M,Nc] = act(A[M,K] @ W[K,Nc] + bias[Nc]); act: 0=none, 1=relu
// obf16: store output as bf16 instead of f32
__global__ __launch_bounds__(256) void gemm_bias(
    const float* __restrict__ A, const float* __restrict__ W,
    const float* __restrict__ bias, void* __restrict__ Cv,
    int M, int K, int Nc, int act, int obf16)
{
    __shared__ float As[16][64];
    __shared__ float Bs[16][64];
    const int r0 = blockIdx.x * 64, c0 = blockIdx.y * 64;
    const int t = threadIdx.x;
    const int tm = t >> 4, tn = t & 15;
    const int lm = t >> 2, lk0 = (t & 3) * 4;
    const int wk = t >> 4, wn0 = (t & 15) * 4;
    float acc[4][4] = {};

    for (int k0 = 0; k0 < K; k0 += 16) {
        float4 a4 = make_float4(0.f, 0.f, 0.f, 0.f);
        if (r0 + lm < M)
            a4 = *(const float4*)(A + (size_t)(r0 + lm) * K + k0 + lk0);
        float4 w4 = *(const float4*)(W + (size_t)(k0 + wk) * Nc + c0 + wn0);
        __syncthreads();
        As[lk0 + 0][lm] = a4.x; As[lk0 + 1][lm] = a4.y;
        As[lk0 + 2][lm] = a4.z; As[lk0 + 3][lm] = a4.w;
        *(float4*)&Bs[wk][wn0] = w4;
        __syncthreads();
        #pragma unroll
        for (int kk = 0; kk < 16; kk++) {
            float4 av = *(const float4*)&As[kk][tm * 4];
            float4 bv = *(const float4*)&Bs[kk][tn * 4];
            float aa[4] = {av.x, av.y, av.z, av.w};
            float bb[4] = {bv.x, bv.y, bv.z, bv.w};
            #pragma unroll
            for (int i = 0; i < 4; i++)
                #pragma unroll
                for (int j = 0; j < 4; j++)
                    acc[i][j] += aa[i] * bb[j];
        }
    }
    #pragma unroll
    for (int i = 0; i < 4; i++) {
        int r = r0 + tm * 4 + i;
        if (r >= M) continue;
        #pragma unroll
        for (int j = 0; j < 4; j++) {
            int c = c0 + tn * 4 + j;
            float v = acc[i][j] + bias[c];
            if (act == 1) v = fmaxf(v, 0.f);
            if (obf16)
                ((__hip_bfloat16*)Cv)[(size_t)r * Nc + c] = __float2bfloat16(v);
            else
                ((float*)Cv)[(size_t)r * Nc + c] = v;
        }
    }
}

// Fused attention, single pass (online softmax). One WAVE per dst node:
// lane = head*8 + sub; each lane owns 2 of the 16 head dims. Per edge the wave
// reads one contiguous 256B bf16 K-row and V-row; dot via 3 shfl_xor in the
// 8-lane head group. Writes normalized aggregate in-place over q.
__global__ __launch_bounds__(256) void attn_fused(
    const float* __restrict__ q, const __hip_bfloat16* __restrict__ k,
    const __hip_bfloat16* __restrict__ v,
    const int* __restrict__ ptr, const int* __restrict__ ssrc,
    float* __restrict__ aggout)
{
    int wid = threadIdx.x >> 6, lane = threadIdx.x & 63;
    int d = blockIdx.x * 4 + wid;
    if (d >= N_NODES) return;
    int col = (lane >> 3) * DH + (lane & 7) * 2;   // head*16 + sub*2

    float2 qv = *(const float2*)(q + (size_t)d * D + col);
    int beg = ptr[d], end = ptr[d + 1];

    float mx = -INFINITY, den = 0.f, a0 = 0.f, a1 = 0.f;
    for (int i = beg; i < end; i++) {
        int s = ssrc[i];
        unsigned int ku = *(const unsigned int*)(k + (size_t)s * D + col);
        unsigned int vu = *(const unsigned int*)(v + (size_t)s * D + col);
        float k0 = __uint_as_float(ku << 16);
        float k1 = __uint_as_float(ku & 0xffff0000u);
        float p = qv.x * k0 + qv.y * k1;
        p += __shfl_xor(p, 1);
        p += __shfl_xor(p, 2);
        p += __shfl_xor(p, 4);
        p *= 0.25f;                                  // 1/sqrt(16)
        if (p > mx) {
            float f = __expf(mx - p);                // first time: exp(-inf)=0, state is 0 anyway
            den *= f; a0 *= f; a1 *= f;
            mx = p;
        }
        float w = __expf(p - mx);
        den += w;
        a0 += w * __uint_as_float(vu << 16);
        a1 += w * __uint_as_float(vu & 0xffff0000u);
    }
    float r = 1.f / (den + 1e-9f);
    float2 o; o.x = a0 * r; o.y = a1 * r;
    *(float2*)(aggout + (size_t)d * D + col) = o;
}

// out = LN(a + b) * g + be ; one wave per row; out may alias a
__global__ void ln_fused(const float* __restrict__ a, const float* __restrict__ b,
                         const float* __restrict__ g, const float* __restrict__ be,
                         float* __restrict__ out, int M)
{
    int wid = threadIdx.x >> 6, lane = threadIdx.x & 63;
    int row = blockIdx.x * 4 + wid;
    if (row >= M) return;
    const float* ar = a + (size_t)row * D;
    const float* br = b + (size_t)row * D;
    float x1 = ar[lane] + br[lane];
    float x2 = ar[lane + 64] + br[lane + 64];
    float s = x1 + x2;
    #pragma unroll
    for (int o = 32; o > 0; o >>= 1) s += __shfl_xor(s, o);
    float mean = s * (1.f / 128.f);
    float d1 = x1 - mean, d2 = x2 - mean;
    float vs = d1 * d1 + d2 * d2;
    #pragma unroll
    for (int o = 32; o > 0; o >>= 1) vs += __shfl_xor(vs, o);
    float rstd = rsqrtf(vs * (1.f / 128.f) + 1e-5f);
    float* orow = out + (size_t)row * D;
    orow[lane]      = d1 * rstd * g[lane]      + be[lane];
    orow[lane + 64] = d2 * rstd * g[lane + 64] + be[lane + 64];
}

__global__ void predict_kernel(const float* __restrict__ h,
                               const int* __restrict__ ai, const int* __restrict__ bi,
                               const float* __restrict__ Wp1, const float* __restrict__ bp1,
                               const float* __restrict__ Wp2, const float* __restrict__ bp2,
                               float* __restrict__ out)
{
    __shared__ float z[128];
    int p = blockIdx.x;
    int a = ai[p], b = bi[p];
    int t = threadIdx.x;
    z[t]      = h[(size_t)a * D + t]      * h[(size_t)b * D + t];
    z[t + 64] = h[(size_t)a * D + t + 64] * h[(size_t)b * D + t + 64];
    __syncthreads();
    float acc = bp1[t];
    #pragma unroll 4
    for (int i = 0; i < 128; i++) acc += z[i] * Wp1[(size_t)i * 64 + t];
    acc = acc > 0.f ? acc : 0.2f * acc;
    float part = acc * Wp2[t];
    #pragma unroll
    for (int o = 32; o > 0; o >>= 1) part += __shfl_down(part, o);
    if (t == 0) out[p] = part + bp2[0];
}

extern "C" void kernel_launch(void* const* d_in, const int* in_sizes, int n_in,
                              void* d_out, int out_size, void* d_ws, size_t ws_size,
                              hipStream_t stream)
{
    const float* x       = (const float*)d_in[0];
    const int*   src     = (const int*)d_in[1];
    const int*   dst     = (const int*)d_in[2];
    const int*   pos_src = (const int*)d_in[3];
    const int*   pos_dst = (const int*)d_in[4];
    const int*   neg_src = (const int*)d_in[5];
    const int*   neg_dst = (const int*)d_in[6];
    const float* W_in = (const float*)d_in[7];
    const float* b_in = (const float*)d_in[8];
    const float* Wq = (const float*)d_in[9];
    const float* bq = (const float*)d_in[10];
    const float* Wk = (const float*)d_in[11];
    const float* bk = (const float*)d_in[12];
    const float* Wv = (const float*)d_in[13];
    const float* bv = (const float*)d_in[14];
    const float* Wo = (const float*)d_in[15];
    const float* bo = (const float*)d_in[16];
    const float* ln1g = (const float*)d_in[17];
    const float* ln1b = (const float*)d_in[18];
    const float* Wf1 = (const float*)d_in[19];
    const float* bf1 = (const float*)d_in[20];
    const float* Wf2 = (const float*)d_in[21];
    const float* bf2 = (const float*)d_in[22];
    const float* ln2g = (const float*)d_in[23];
    const float* ln2b = (const float*)d_in[24];
    const float* Wp1 = (const float*)d_in[25];
    const float* bp1 = (const float*)d_in[26];
    const float* Wp2 = (const float*)d_in[27];
    const float* bp2 = (const float*)d_in[28];

    float* out = (float*)d_out;
    float* h   = out + 2 * PP;              // h lives directly in d_out

    const size_t S = (size_t)N_NODES * D;   // 6.4M floats
    float* ws = (float*)d_ws;
    float* q    = ws;                        // [N,D] f32: q -> agg (in-place); ff spans [0,2S)
    float* tmp  = ws + S;                    // [N,D] f32 GEMM tmp
    __hip_bfloat16* kb = (__hip_bfloat16*)(ws + 2 * S);          // [N,D] bf16
    __hip_bfloat16* vb = (__hip_bfloat16*)(ws + 2 * S + S / 2);  // [N,D] bf16
    float* tmp2 = ws + 2 * S;                // [N,D] f32 (aliases kb/vb, used after attn)
    int*   ptr  = (int*)(ws + 3 * S);        // [N+1]
    int*   cnt  = ptr + (N_NODES + 1);       // [N]
    int*   ssrc = cnt + N_NODES;             // [E]
    float* ff   = ws;                        // [N,FF] spans q+tmp slots

    auto cdiv = [](int a, int b) { return (a + b - 1) / b; };
    const int gM = cdiv(N_NODES, 64);

    // h = x @ W_in + b_in
    gemm_bias<<<dim3(gM, D / 64), 256, 0, stream>>>(x, W_in, b_in, h, N_NODES, IN_F, D, 0, 0);

    for (int l = 0; l < NLAYER; l++) {
        const int* sl = src + (size_t)l * NE;
        const int* dl = dst + (size_t)l * NE;

        // --- CSR build over dst (ssrc = src ids bucketed by dst) ---
        fill_int<<<cdiv(N_NODES, 256), 256, 0, stream>>>(cnt, 0, N_NODES);
        count_kernel<<<cdiv(NE, 256), 256, 0, stream>>>(dl, cnt);
        scan_kernel<<<1, 1024, 0, stream>>>(cnt, ptr);
        fill_int<<<cdiv(N_NODES, 256), 256, 0, stream>>>(cnt, 0, N_NODES);
        scatter_kernel<<<cdiv(NE, 256), 256, 0, stream>>>(dl, sl, ptr, cnt, ssrc);

        // --- projections (k, v stored bf16) ---
        gemm_bias<<<dim3(gM, D / 64), 256, 0, stream>>>(h, Wq + (size_t)l * D * D, bq + l * D, q,  N_NODES, D, D, 0, 0);
        gemm_bias<<<dim3(gM, D / 64), 256, 0, stream>>>(h, Wk + (size_t)l * D * D, bk + l * D, kb, N_NODES, D, D, 0, 1);
        gemm_bias<<<dim3(gM, D / 64), 256, 0, stream>>>(h, Wv + (size_t)l * D * D, bv + l * D, vb, N_NODES, D, D, 0, 1);

        // --- fused single-pass attention (agg in-place over q) ---
        attn_fused<<<cdiv(N_NODES, 4), 256, 0, stream>>>(q, kb, vb, ptr, ssrc, q);

        // attn out = agg @ Wo + bo -> tmp ; h = LN(h + tmp)
        gemm_bias<<<dim3(gM, D / 64), 256, 0, stream>>>(q, Wo + (size_t)l * D * D, bo + l * D, tmp, N_NODES, D, D, 0, 0);
        ln_fused<<<cdiv(N_NODES, 4), 256, 0, stream>>>(h, tmp, ln1g + l * D, ln1b + l * D, h, N_NODES);

        // FFN: ff = relu(h @ Wf1 + bf1) ; tmp2 = ff @ Wf2 + bf2 ; h = LN(h + tmp2)
        gemm_bias<<<dim3(gM, FF / 64), 256, 0, stream>>>(h, Wf1 + (size_t)l * D * FF, bf1 + l * FF, ff, N_NODES, D, FF, 1, 0);
        gemm_bias<<<dim3(gM, D / 64), 256, 0, stream>>>(ff, Wf2 + (size_t)l * FF * D, bf2 + l * D, tmp2, N_NODES, FF, D, 0, 0);
        ln_fused<<<cdiv(N_NODES, 4), 256, 0, stream>>>(h, tmp2, ln2g + l * D, ln2b + l * D, h, N_NODES);
    }

    predict_kernel<<<PP, 64, 0, stream>>>(h, pos_src, pos_dst, Wp1, bp1, Wp2, bp2, out);
    predict_kernel<<<PP, 64, 0, stream>>>(h, neg_src, neg_dst, Wp1, bp1, Wp2, bp2, out + PP);
}

// Round 5
// 899.427 us; speedup vs baseline: 4.0003x; 1.2491x over previous
//
#include <hip/hip_runtime.h>
#include <hip/hip_bf16.h>
#include <math.h>

#define N_NODES 50000
#define NE      800000
#define D       128
#define H       8
#define DH      16
#define NLAYER  2
#define IN_F    128
#define PP      8192
#define FF      256
#define MPAD    50048   // 391 * 128

typedef short  bf16x8 __attribute__((ext_vector_type(8)));
typedef float  f32x4  __attribute__((ext_vector_type(4)));
typedef __hip_bfloat16 bf16;

__global__ void fill_int(int* __restrict__ p, int v, int n) {
    int i = blockIdx.x * blockDim.x + threadIdx.x;
    if (i < n) p[i] = v;
}

__global__ void count_kernel(const int* __restrict__ dst, int* __restrict__ cnt) {
    int e = blockIdx.x * blockDim.x + threadIdx.x;
    if (e < NE) atomicAdd(&cnt[dst[e]], 1);
}

__global__ __launch_bounds__(1024) void scan_kernel(const int* __restrict__ cnt, int* __restrict__ ptr) {
    __shared__ int sdata[1024];
    __shared__ int soff;
    if (threadIdx.x == 0) soff = 0;
    __syncthreads();
    for (int base = 0; base < N_NODES; base += 1024) {
        int i = base + threadIdx.x;
        int v = (i < N_NODES) ? cnt[i] : 0;
        sdata[threadIdx.x] = v;
        __syncthreads();
        #pragma unroll
        for (int o = 1; o < 1024; o <<= 1) {
            int t = (threadIdx.x >= o) ? sdata[threadIdx.x - o] : 0;
            __syncthreads();
            sdata[threadIdx.x] += t;
            __syncthreads();
        }
        if (i < N_NODES) ptr[i] = soff + sdata[threadIdx.x] - v;
        __syncthreads();
        if (threadIdx.x == 1023) soff += sdata[1023];
        __syncthreads();
    }
    if (threadIdx.x == 0) ptr[N_NODES] = soff;
}

__global__ void scatter_kernel(const int* __restrict__ dst, const int* __restrict__ src,
                               const int* __restrict__ ptr, int* __restrict__ cnt,
                               int* __restrict__ ssrc) {
    int e = blockIdx.x * blockDim.x + threadIdx.x;
    if (e < NE) {
        int d = dst[e];
        int pos = ptr[d] + atomicAdd(&cnt[d], 1);
        ssrc[pos] = src[e];
    }
}

// x (f32, N rows) -> xb (bf16, MPAD rows; pad rows = 0)
__global__ void xb_kernel(const float* __restrict__ x, bf16* __restrict__ xb) {
    int id = blockIdx.x * blockDim.x + threadIdx.x;
    if (id >= MPAD * IN_F) return;
    int r = id / IN_F;
    xb[id] = __float2bfloat16(r < N_NODES ? x[id] : 0.f);
}

// Wt[b][n][k] = bf16(W[b][k][n]); grid.y = batch
__global__ void wt_kernel(const float* __restrict__ W, bf16* __restrict__ Wt, int K, int N) {
    size_t base = (size_t)blockIdx.y * K * N;
    int id = blockIdx.x * blockDim.x + threadIdx.x;
    if (id >= K * N) return;
    int n = id / K, k = id - n * K;
    Wt[base + id] = __float2bfloat16(W[base + (size_t)k * N + n]);
}

// C[M,Nc] = act(A[M,K] @ W[K,Nc] + bias); A bf16 [MPAD,K], Wt bf16 [Nc,K] (transposed).
// 128x128 tile, 4 waves (2x2), each 64x64 via 4x4 frags of mfma_f32_16x16x32_bf16.
// LDS XOR-swizzled (T2) to keep frag ds_read_b128 ~conflict-free.
__global__ __launch_bounds__(256) void gemm_mfma(
    const bf16* __restrict__ A, const bf16* __restrict__ Wt,
    const float* __restrict__ bias,
    float* __restrict__ Cf, bf16* __restrict__ Cb,
    int Mvalid, int K, int Nc, int relu)
{
    __shared__ float4 As4[1024];   // 128 rows x 128B
    __shared__ float4 Bs4[1024];
    char* As = (char*)As4;
    char* Bs = (char*)Bs4;
    const int t = threadIdx.x;
    const int wave = t >> 6, lane = t & 63;
    const int wr = wave >> 1, wc = wave & 1;
    const int r0 = blockIdx.x * 128, c0 = blockIdx.y * 128;

    f32x4 acc[4][4] = {};

    const int lrow   = t >> 3;         // 0..31
    const int lcol16 = (t & 7) * 16;   // byte col within 128B row

    for (int k0 = 0; k0 < K; k0 += 64) {
        #pragma unroll
        for (int p = 0; p < 4; p++) {
            int row = p * 32 + lrow;
            float4 av = *(const float4*)((const char*)(A  + (size_t)(r0 + row) * K + k0) + lcol16);
            float4 bv = *(const float4*)((const char*)(Wt + (size_t)(c0 + row) * K + k0) + lcol16);
            int sw = lcol16 ^ ((row & 7) << 4);
            *(float4*)(As + row * 128 + sw) = av;
            *(float4*)(Bs + row * 128 + sw) = bv;
        }
        __syncthreads();
        #pragma unroll
        for (int kk = 0; kk < 2; kk++) {
            bf16x8 af[4], bfr[4];
            int kbyte = kk * 64 + (lane >> 4) * 16;
            #pragma unroll
            for (int m = 0; m < 4; m++) {
                int rowa = wr * 64 + m * 16 + (lane & 15);
                af[m]  = *(const bf16x8*)(As + rowa * 128 + (kbyte ^ ((rowa & 7) << 4)));
                int rowb = wc * 64 + m * 16 + (lane & 15);
                bfr[m] = *(const bf16x8*)(Bs + rowb * 128 + (kbyte ^ ((rowb & 7) << 4)));
            }
            #pragma unroll
            for (int m = 0; m < 4; m++)
                #pragma unroll
                for (int n = 0; n < 4; n++)
                    acc[m][n] = __builtin_amdgcn_mfma_f32_16x16x32_bf16(af[m], bfr[n], acc[m][n], 0, 0, 0);
        }
        __syncthreads();
    }

    const int colbase = c0 + wc * 64 + (lane & 15);
    const int rowbase = r0 + wr * 64 + ((lane >> 4) << 2);
    #pragma unroll
    for (int n = 0; n < 4; n++) {
        int col = colbase + n * 16;
        float bsv = bias[col];
        #pragma unroll
        for (int m = 0; m < 4; m++) {
            #pragma unroll
            for (int i = 0; i < 4; i++) {
                int row = rowbase + m * 16 + i;
                if (row < Mvalid) {
                    float v = acc[m][n][i] + bsv;
                    if (relu) v = fmaxf(v, 0.f);
                    if (Cf) Cf[(size_t)row * Nc + col] = v;
                    if (Cb) Cb[(size_t)row * Nc + col] = __float2bfloat16(v);
                }
            }
        }
    }
}

// Fused single-pass attention (online softmax). One wave per dst node:
// lane = head*8 + sub; each lane owns 2 of the 16 head dims. q,k,v bf16.
__global__ __launch_bounds__(256) void attn_fused(
    const bf16* __restrict__ q, const bf16* __restrict__ k, const bf16* __restrict__ v,
    const int* __restrict__ ptr, const int* __restrict__ ssrc,
    bf16* __restrict__ aggout)
{
    int wid = threadIdx.x >> 6, lane = threadIdx.x & 63;
    int d = blockIdx.x * 4 + wid;
    if (d >= N_NODES) return;
    int col = (lane >> 3) * DH + (lane & 7) * 2;

    unsigned int qu = *(const unsigned int*)(q + (size_t)d * D + col);
    float qx = __uint_as_float(qu << 16);
    float qy = __uint_as_float(qu & 0xffff0000u);
    int beg = ptr[d], end = ptr[d + 1];

    float mx = -INFINITY, den = 0.f, a0 = 0.f, a1 = 0.f;
    for (int i = beg; i < end; i++) {
        int s = ssrc[i];
        unsigned int ku = *(const unsigned int*)(k + (size_t)s * D + col);
        unsigned int vu = *(const unsigned int*)(v + (size_t)s * D + col);
        float p = qx * __uint_as_float(ku << 16) + qy * __uint_as_float(ku & 0xffff0000u);
        p += __shfl_xor(p, 1);
        p += __shfl_xor(p, 2);
        p += __shfl_xor(p, 4);
        p *= 0.25f;
        if (p > mx) {
            float f = __expf(mx - p);
            den *= f; a0 *= f; a1 *= f;
            mx = p;
        }
        float w = __expf(p - mx);
        den += w;
        a0 += w * __uint_as_float(vu << 16);
        a1 += w * __uint_as_float(vu & 0xffff0000u);
    }
    float r = 1.f / (den + 1e-9f);
    bf16* op = aggout + (size_t)d * D + col;
    op[0] = __float2bfloat16(a0 * r);
    op[1] = __float2bfloat16(a1 * r);
}

// h = LN(a + b)*g + be ; writes f32 out AND bf16 shadow; out may alias a
__global__ void ln_fused(const float* __restrict__ a, const float* __restrict__ b,
                         const float* __restrict__ g, const float* __restrict__ be,
                         float* __restrict__ out, bf16* __restrict__ outb, int M)
{
    int wid = threadIdx.x >> 6, lane = threadIdx.x & 63;
    int row = blockIdx.x * 4 + wid;
    if (row >= M) return;
    const float* ar = a + (size_t)row * D;
    const float* br = b + (size_t)row * D;
    float x1 = ar[lane] + br[lane];
    float x2 = ar[lane + 64] + br[lane + 64];
    float s = x1 + x2;
    #pragma unroll
    for (int o = 32; o > 0; o >>= 1) s += __shfl_xor(s, o);
    float mean = s * (1.f / 128.f);
    float d1 = x1 - mean, d2 = x2 - mean;
    float vs = d1 * d1 + d2 * d2;
    #pragma unroll
    for (int o = 32; o > 0; o >>= 1) vs += __shfl_xor(vs, o);
    float rstd = rsqrtf(vs * (1.f / 128.f) + 1e-5f);
    float o1 = d1 * rstd * g[lane]      + be[lane];
    float o2 = d2 * rstd * g[lane + 64] + be[lane + 64];
    float* orow = out + (size_t)row * D;
    orow[lane] = o1; orow[lane + 64] = o2;
    bf16* obr = outb + (size_t)row * D;
    obr[lane] = __float2bfloat16(o1); obr[lane + 64] = __float2bfloat16(o2);
}

__global__ void predict_kernel(const float* __restrict__ h,
                               const int* __restrict__ ai, const int* __restrict__ bi,
                               const float* __restrict__ Wp1, const float* __restrict__ bp1,
                               const float* __restrict__ Wp2, const float* __restrict__ bp2,
                               float* __restrict__ out)
{
    __shared__ float z[128];
    int p = blockIdx.x;
    int a = ai[p], b = bi[p];
    int t = threadIdx.x;
    z[t]      = h[(size_t)a * D + t]      * h[(size_t)b * D + t];
    z[t + 64] = h[(size_t)a * D + t + 64] * h[(size_t)b * D + t + 64];
    __syncthreads();
    float acc = bp1[t];
    #pragma unroll 4
    for (int i = 0; i < 128; i++) acc += z[i] * Wp1[(size_t)i * 64 + t];
    acc = acc > 0.f ? acc : 0.2f * acc;
    float part = acc * Wp2[t];
    #pragma unroll
    for (int o = 32; o > 0; o >>= 1) part += __shfl_down(part, o);
    if (t == 0) out[p] = part + bp2[0];
}

extern "C" void kernel_launch(void* const* d_in, const int* in_sizes, int n_in,
                              void* d_out, int out_size, void* d_ws, size_t ws_size,
                              hipStream_t stream)
{
    const float* x       = (const float*)d_in[0];
    const int*   src     = (const int*)d_in[1];
    const int*   dst     = (const int*)d_in[2];
    const int*   pos_src = (const int*)d_in[3];
    const int*   pos_dst = (const int*)d_in[4];
    const int*   neg_src = (const int*)d_in[5];
    const int*   neg_dst = (const int*)d_in[6];
    const float* W_in = (const float*)d_in[7];
    const float* b_in = (const float*)d_in[8];
    const float* Wq = (const float*)d_in[9];
    const float* bq = (const float*)d_in[10];
    const float* Wk = (const float*)d_in[11];
    const float* bk = (const float*)d_in[12];
    const float* Wv = (const float*)d_in[13];
    const float* bv = (const float*)d_in[14];
    const float* Wo = (const float*)d_in[15];
    const float* bo = (const float*)d_in[16];
    const float* ln1g = (const float*)d_in[17];
    const float* ln1b = (const float*)d_in[18];
    const float* Wf1 = (const float*)d_in[19];
    const float* bf1 = (const float*)d_in[20];
    const float* Wf2 = (const float*)d_in[21];
    const float* bf2 = (const float*)d_in[22];
    const float* ln2g = (const float*)d_in[23];
    const float* ln2b = (const float*)d_in[24];
    const float* Wp1 = (const float*)d_in[25];
    const float* bp1 = (const float*)d_in[26];
    const float* Wp2 = (const float*)d_in[27];
    const float* bp2 = (const float*)d_in[28];

    float* out = (float*)d_out;
    float* h   = out + 2 * PP;                      // [N,D] f32 residual stream

    const size_t SP = (size_t)MPAD * D;             // 6,406,144 elems
    float* ws = (float*)d_ws;
    // f32-unit offsets (see journal): total ~91 MB
    bf16* q    = (bf16*)ws;                         // [MPAD,D] bf16
    bf16* aggb = q + SP;                            // [MPAD,D] bf16
    bf16* ffb  = (bf16*)ws;                         // [MPAD,FF] bf16, spans q+aggb
    float* tmp = ws + SP;                           // [MPAD,D] f32
    bf16* xb   = (bf16*)tmp;                        // [MPAD,D] bf16 (dead before tmp used)
    bf16* hb   = (bf16*)(ws + 2 * SP);              // [MPAD,D] bf16
    bf16* kb   = hb + SP;
    bf16* vb   = kb + SP;
    int*  ib   = (int*)(vb + SP);
    int*  ptr  = ib;                                // [N+1]
    int*  cnt  = ib + 50052;                        // [N]
    int*  ssrc = cnt + N_NODES;                     // [E]
    bf16* wtb  = (bf16*)(ssrc + NE);
    bf16* win_t = wtb;                              // 16384
    bf16* wq_t  = wtb + 16384;                      // 2*16384
    bf16* wk_t  = wtb + 49152;
    bf16* wv_t  = wtb + 81920;
    bf16* wo_t  = wtb + 114688;
    bf16* wf1_t = wtb + 147456;                     // 2*32768  [256][128] per layer
    bf16* wf2_t = wtb + 212992;                     // 2*32768  [128][256] per layer

    auto cdiv = [](int a, int b) { return (a + b - 1) / b; };
    const int GX = MPAD / 128;                      // 391

    // one-time converts (cheap, inside graph: deterministic)
    xb_kernel<<<cdiv(MPAD * IN_F, 256), 256, 0, stream>>>(x, xb);
    wt_kernel<<<dim3(64, 1), 256, 0, stream>>>(W_in, win_t, 128, 128);
    wt_kernel<<<dim3(64, NLAYER), 256, 0, stream>>>(Wq, wq_t, 128, 128);
    wt_kernel<<<dim3(64, NLAYER), 256, 0, stream>>>(Wk, wk_t, 128, 128);
    wt_kernel<<<dim3(64, NLAYER), 256, 0, stream>>>(Wv, wv_t, 128, 128);
    wt_kernel<<<dim3(64, NLAYER), 256, 0, stream>>>(Wo, wo_t, 128, 128);
    wt_kernel<<<dim3(128, NLAYER), 256, 0, stream>>>(Wf1, wf1_t, 128, 256);
    wt_kernel<<<dim3(128, NLAYER), 256, 0, stream>>>(Wf2, wf2_t, 256, 128);

    // h = x @ W_in + b_in   (f32 into d_out, bf16 shadow)
    gemm_mfma<<<dim3(GX, 1), 256, 0, stream>>>(xb, win_t, b_in, h, hb, N_NODES, 128, 128, 0);

    for (int l = 0; l < NLAYER; l++) {
        const int* sl = src + (size_t)l * NE;
        const int* dl = dst + (size_t)l * NE;

        fill_int<<<cdiv(N_NODES, 256), 256, 0, stream>>>(cnt, 0, N_NODES);
        count_kernel<<<cdiv(NE, 256), 256, 0, stream>>>(dl, cnt);
        scan_kernel<<<1, 1024, 0, stream>>>(cnt, ptr);
        fill_int<<<cdiv(N_NODES, 256), 256, 0, stream>>>(cnt, 0, N_NODES);
        scatter_kernel<<<cdiv(NE, 256), 256, 0, stream>>>(dl, sl, ptr, cnt, ssrc);

        gemm_mfma<<<dim3(GX, 1), 256, 0, stream>>>(hb, wq_t + l * 16384, bq + l * D, nullptr, q,  MPAD, 128, 128, 0);
        gemm_mfma<<<dim3(GX, 1), 256, 0, stream>>>(hb, wk_t + l * 16384, bk + l * D, nullptr, kb, MPAD, 128, 128, 0);
        gemm_mfma<<<dim3(GX, 1), 256, 0, stream>>>(hb, wv_t + l * 16384, bv + l * D, nullptr, vb, MPAD, 128, 128, 0);

        attn_fused<<<cdiv(N_NODES, 4), 256, 0, stream>>>(q, kb, vb, ptr, ssrc, aggb);

        gemm_mfma<<<dim3(GX, 1), 256, 0, stream>>>(aggb, wo_t + l * 16384, bo + l * D, tmp, nullptr, MPAD, 128, 128, 0);
        ln_fused<<<cdiv(N_NODES, 4), 256, 0, stream>>>(h, tmp, ln1g + l * D, ln1b + l * D, h, hb, N_NODES);

        gemm_mfma<<<dim3(GX, 2), 256, 0, stream>>>(hb, wf1_t + l * 32768, bf1 + l * FF, nullptr, ffb, MPAD, 128, 256, 1);
        gemm_mfma<<<dim3(GX, 1), 256, 0, stream>>>(ffb, wf2_t + l * 32768, bf2 + l * D, tmp, nullptr, MPAD, 256, 128, 0);
        ln_fused<<<cdiv(N_NODES, 4), 256, 0, stream>>>(h, tmp, ln2g + l * D, ln2b + l * D, h, hb, N_NODES);
    }

    predict_kernel<<<PP, 64, 0, stream>>>(h, pos_src, pos_dst, Wp1, bp1, Wp2, bp2, out);
    predict_kernel<<<PP, 64, 0, stream>>>(h, neg_src, neg_dst, Wp1, bp1, Wp2, bp2, out + PP);
}

// Round 6
// 789.672 us; speedup vs baseline: 4.5563x; 1.1390x over previous
//
#include <hip/hip_runtime.h>
#include <hip/hip_bf16.h>
#include <math.h>

#define N_NODES 50000
#define NE      800000
#define D       128
#define H       8
#define DH      16
#define NLAYER  2
#define IN_F    128
#define PP      8192
#define FF      256
#define MPAD    50048   // 391 * 128

typedef short  bf16x8 __attribute__((ext_vector_type(8)));
typedef float  f32x4  __attribute__((ext_vector_type(4)));
typedef __hip_bfloat16 bf16;

__device__ __forceinline__ float bflo(unsigned int u) { return __uint_as_float(u << 16); }
__device__ __forceinline__ float bfhi(unsigned int u) { return __uint_as_float(u & 0xffff0000u); }

__global__ void count_kernel(const int* __restrict__ dst, int* __restrict__ cnt) {
    int e = blockIdx.x * blockDim.x + threadIdx.x;
    if (e < NE) atomicAdd(&cnt[dst[e]], 1);
}

// chunked exclusive scan: 1024 threads, each owns 49 contiguous elems
__global__ __launch_bounds__(1024) void scan_kernel(const int* __restrict__ cnt, int* __restrict__ ptr) {
    __shared__ int ssum[1024];
    const int CH = 49;
    int t = threadIdx.x;
    int b0 = t * CH;
    int s = 0;
    for (int j = 0; j < CH; j++) {
        int i = b0 + j;
        if (i < N_NODES) s += cnt[i];
    }
    ssum[t] = s;
    __syncthreads();
    for (int o = 1; o < 1024; o <<= 1) {
        int v = (t >= o) ? ssum[t - o] : 0;
        __syncthreads();
        ssum[t] += v;
        __syncthreads();
    }
    int base = ssum[t] - s;
    for (int j = 0; j < CH; j++) {
        int i = b0 + j;
        if (i < N_NODES) { ptr[i] = base; base += cnt[i]; }
    }
    if (t == 1023) ptr[N_NODES] = base;
}

__global__ void scatter_kernel(const int* __restrict__ dst, const int* __restrict__ src,
                               const int* __restrict__ ptr, int* __restrict__ cnt,
                               int* __restrict__ ssrc) {
    int e = blockIdx.x * blockDim.x + threadIdx.x;
    if (e < NE) {
        int d = dst[e];
        int pos = ptr[d] + atomicAdd(&cnt[d], 1);
        ssrc[pos] = src[e];
    }
}

__global__ void xb_kernel(const float* __restrict__ x, bf16* __restrict__ xb) {
    int id = blockIdx.x * blockDim.x + threadIdx.x;
    if (id >= MPAD * IN_F) return;
    int r = id / IN_F;
    xb[id] = __float2bfloat16(r < N_NODES ? x[id] : 0.f);
}

// Wt[obase + n*K + k] = bf16(W[ibase + k*N + n]); grid.y = batch
__global__ void wt_kernel(const float* __restrict__ W, bf16* __restrict__ Wt,
                          int K, int N, int ostride) {
    size_t ibase = (size_t)blockIdx.y * K * N;
    size_t obase = (size_t)blockIdx.y * ostride;
    int id = blockIdx.x * blockDim.x + threadIdx.x;
    if (id >= K * N) return;
    int n = id / K, k = id - n * K;
    Wt[obase + id] = __float2bfloat16(W[ibase + (size_t)k * N + n]);
}

__global__ void bcat_kernel(const float* __restrict__ bq, const float* __restrict__ bk,
                            const float* __restrict__ bv, float* __restrict__ bqkv) {
    int i = blockIdx.x * blockDim.x + threadIdx.x;
    if (i >= NLAYER * 384) return;
    int l = i / 384, c = i - l * 384;
    float v = (c < 128) ? bq[l * 128 + c] : (c < 256 ? bk[l * 128 + c - 128] : bv[l * 128 + c - 256]);
    bqkv[i] = v;
}

// C[M,Nc] = act(A[M,K] @ W + bias); A bf16 [*,lda], Wt bf16 [Nc,K] transposed.
// 128x128 tile, 4 waves (2x2), 4x4 frags of mfma_f32_16x16x32_bf16, XOR-swizzled LDS.
__global__ __launch_bounds__(256) void gemm_mfma(
    const bf16* __restrict__ A, const bf16* __restrict__ Wt,
    const float* __restrict__ bias,
    float* __restrict__ Cf, bf16* __restrict__ Cb,
    int Mvalid, int K, int Nc, int lda, int relu)
{
    __shared__ float4 As4[1024];
    __shared__ float4 Bs4[1024];
    char* As = (char*)As4;
    char* Bs = (char*)Bs4;
    const int t = threadIdx.x;
    const int wave = t >> 6, lane = t & 63;
    const int wr = wave >> 1, wc = wave & 1;
    const int r0 = blockIdx.x * 128, c0 = blockIdx.y * 128;

    f32x4 acc[4][4] = {};

    const int lrow   = t >> 3;
    const int lcol16 = (t & 7) * 16;

    for (int k0 = 0; k0 < K; k0 += 64) {
        #pragma unroll
        for (int p = 0; p < 4; p++) {
            int row = p * 32 + lrow;
            float4 av = *(const float4*)((const char*)(A  + (size_t)(r0 + row) * lda + k0) + lcol16);
            float4 bv = *(const float4*)((const char*)(Wt + (size_t)(c0 + row) * K + k0) + lcol16);
            int sw = lcol16 ^ ((row & 7) << 4);
            *(float4*)(As + row * 128 + sw) = av;
            *(float4*)(Bs + row * 128 + sw) = bv;
        }
        __syncthreads();
        #pragma unroll
        for (int kk = 0; kk < 2; kk++) {
            bf16x8 af[4], bfr[4];
            int kbyte = kk * 64 + (lane >> 4) * 16;
            #pragma unroll
            for (int m = 0; m < 4; m++) {
                int rowa = wr * 64 + m * 16 + (lane & 15);
                af[m]  = *(const bf16x8*)(As + rowa * 128 + (kbyte ^ ((rowa & 7) << 4)));
                int rowb = wc * 64 + m * 16 + (lane & 15);
                bfr[m] = *(const bf16x8*)(Bs + rowb * 128 + (kbyte ^ ((rowb & 7) << 4)));
            }
            #pragma unroll
            for (int m = 0; m < 4; m++)
                #pragma unroll
                for (int n = 0; n < 4; n++)
                    acc[m][n] = __builtin_amdgcn_mfma_f32_16x16x32_bf16(af[m], bfr[n], acc[m][n], 0, 0, 0);
        }
        __syncthreads();
    }

    const int colbase = c0 + wc * 64 + (lane & 15);
    const int rowbase = r0 + wr * 64 + ((lane >> 4) << 2);
    #pragma unroll
    for (int n = 0; n < 4; n++) {
        int col = colbase + n * 16;
        float bsv = bias[col];
        #pragma unroll
        for (int m = 0; m < 4; m++) {
            #pragma unroll
            for (int i = 0; i < 4; i++) {
                int row = rowbase + m * 16 + i;
                if (row < Mvalid) {
                    float v = acc[m][n][i] + bsv;
                    if (relu) v = fmaxf(v, 0.f);
                    if (Cf) Cf[(size_t)row * Nc + col] = v;
                    if (Cb) Cb[(size_t)row * Nc + col] = __float2bfloat16(v);
                }
            }
        }
    }
}

// Fused single-pass attention on qkv[M][384] (q|k|v). One wave per dst node.
// lane = slot*8 + h: lane owns full 16-dim head h for edges beg+slot, +8, +16, ...
// No cross-lane ops in the edge loop; one 3-level online-state merge per node.
// Writes normalized aggregate in-place over the q section.
__global__ __launch_bounds__(256) void attn_fused(
    const bf16* __restrict__ qkv,
    const int* __restrict__ ptr, const int* __restrict__ ssrc,
    bf16* __restrict__ aggout)
{
    int wid = threadIdx.x >> 6, lane = threadIdx.x & 63;
    int d = blockIdx.x * 4 + wid;
    if (d >= N_NODES) return;
    int slot = lane >> 3, h = lane & 7;

    // q slice for head h (16 bf16 = 32B)
    const unsigned int* qr = (const unsigned int*)(qkv + (size_t)d * 384 + h * DH);
    float qf[16];
    {
        uint4 q0 = *(const uint4*)(qr);
        uint4 q1 = *(const uint4*)(qr + 4);
        qf[0]=bflo(q0.x); qf[1]=bfhi(q0.x); qf[2]=bflo(q0.y); qf[3]=bfhi(q0.y);
        qf[4]=bflo(q0.z); qf[5]=bfhi(q0.z); qf[6]=bflo(q0.w); qf[7]=bfhi(q0.w);
        qf[8]=bflo(q1.x); qf[9]=bfhi(q1.x); qf[10]=bflo(q1.y); qf[11]=bfhi(q1.y);
        qf[12]=bflo(q1.z); qf[13]=bfhi(q1.z); qf[14]=bflo(q1.w); qf[15]=bfhi(q1.w);
    }

    int beg = ptr[d], end = ptr[d + 1];
    float mx = -INFINITY, den = 0.f;
    float acc[16] = {};

    for (int i = beg + slot; i < end; i += 8) {
        int s = ssrc[i];
        const unsigned int* kr = (const unsigned int*)(qkv + (size_t)s * 384 + 128 + h * DH);
        uint4 k0 = *(const uint4*)(kr);
        uint4 k1 = *(const uint4*)(kr + 4);
        uint4 v0 = *(const uint4*)(kr + 64);   // v slice = k slice + 128 bf16
        uint4 v1 = *(const uint4*)(kr + 68);
        float p = qf[0]*bflo(k0.x) + qf[1]*bfhi(k0.x)
                + qf[2]*bflo(k0.y) + qf[3]*bfhi(k0.y)
                + qf[4]*bflo(k0.z) + qf[5]*bfhi(k0.z)
                + qf[6]*bflo(k0.w) + qf[7]*bfhi(k0.w)
                + qf[8]*bflo(k1.x) + qf[9]*bfhi(k1.x)
                + qf[10]*bflo(k1.y) + qf[11]*bfhi(k1.y)
                + qf[12]*bflo(k1.z) + qf[13]*bfhi(k1.z)
                + qf[14]*bflo(k1.w) + qf[15]*bfhi(k1.w);
        p *= 0.25f;                               // 1/sqrt(16)
        float w;
        if (p > mx) {
            float f = __expf(mx - p);             // first iter: exp(-inf)=0
            den *= f;
            #pragma unroll
            for (int j = 0; j < 16; j++) acc[j] *= f;
            mx = p;
            w = 1.f;
        } else {
            w = __expf(p - mx);
        }
        den += w;
        acc[0]  += w*bflo(v0.x); acc[1]  += w*bfhi(v0.x);
        acc[2]  += w*bflo(v0.y); acc[3]  += w*bfhi(v0.y);
        acc[4]  += w*bflo(v0.z); acc[5]  += w*bfhi(v0.z);
        acc[6]  += w*bflo(v0.w); acc[7]  += w*bfhi(v0.w);
        acc[8]  += w*bflo(v1.x); acc[9]  += w*bfhi(v1.x);
        acc[10] += w*bflo(v1.y); acc[11] += w*bfhi(v1.y);
        acc[12] += w*bflo(v1.z); acc[13] += w*bfhi(v1.z);
        acc[14] += w*bflo(v1.w); acc[15] += w*bfhi(v1.w);
    }

    // merge online states across the 8 slots (lane bits 3..5)
    #pragma unroll
    for (int o = 8; o < 64; o <<= 1) {
        float omx  = __shfl_xor(mx, o);
        float oden = __shfl_xor(den, o);
        float M = fmaxf(mx, omx);
        float fa = (mx  > -INFINITY) ? __expf(mx  - M) : 0.f;
        float fb = (omx > -INFINITY) ? __expf(omx - M) : 0.f;
        den = den * fa + oden * fb;
        #pragma unroll
        for (int j = 0; j < 16; j++) {
            float oa = __shfl_xor(acc[j], o);
            acc[j] = acc[j] * fa + oa * fb;
        }
        mx = M;
    }

    float r = 1.f / (den + 1e-9f);
    // lane (slot,h) writes cols h*16 + slot*2, +1  (compile-time acc indices)
    float o0 = 0.f, o1 = 0.f;
    #pragma unroll
    for (int j = 0; j < 8; j++) {
        if (slot == j) { o0 = acc[2 * j]; o1 = acc[2 * j + 1]; }
    }
    bf16* op = aggout + (size_t)d * 384 + h * DH + slot * 2;
    op[0] = __float2bfloat16(o0 * r);
    op[1] = __float2bfloat16(o1 * r);
}

// h = LN(a + b)*g + be ; writes f32 out AND bf16 shadow; out may alias a
__global__ void ln_fused(const float* __restrict__ a, const float* __restrict__ b,
                         const float* __restrict__ g, const float* __restrict__ be,
                         float* __restrict__ out, bf16* __restrict__ outb, int M)
{
    int wid = threadIdx.x >> 6, lane = threadIdx.x & 63;
    int row = blockIdx.x * 4 + wid;
    if (row >= M) return;
    const float* ar = a + (size_t)row * D;
    const float* br = b + (size_t)row * D;
    float x1 = ar[lane] + br[lane];
    float x2 = ar[lane + 64] + br[lane + 64];
    float s = x1 + x2;
    #pragma unroll
    for (int o = 32; o > 0; o >>= 1) s += __shfl_xor(s, o);
    float mean = s * (1.f / 128.f);
    float d1 = x1 - mean, d2 = x2 - mean;
    float vs = d1 * d1 + d2 * d2;
    #pragma unroll
    for (int o = 32; o > 0; o >>= 1) vs += __shfl_xor(vs, o);
    float rstd = rsqrtf(vs * (1.f / 128.f) + 1e-5f);
    float o1 = d1 * rstd * g[lane]      + be[lane];
    float o2 = d2 * rstd * g[lane + 64] + be[lane + 64];
    float* orow = out + (size_t)row * D;
    orow[lane] = o1; orow[lane + 64] = o2;
    bf16* obr = outb + (size_t)row * D;
    obr[lane] = __float2bfloat16(o1); obr[lane + 64] = __float2bfloat16(o2);
}

__global__ void predict_kernel(const float* __restrict__ h,
                               const int* __restrict__ ai, const int* __restrict__ bi,
                               const float* __restrict__ Wp1, const float* __restrict__ bp1,
                               const float* __restrict__ Wp2, const float* __restrict__ bp2,
                               float* __restrict__ out)
{
    __shared__ float z[128];
    int p = blockIdx.x;
    int a = ai[p], b = bi[p];
    int t = threadIdx.x;
    z[t]      = h[(size_t)a * D + t]      * h[(size_t)b * D + t];
    z[t + 64] = h[(size_t)a * D + t + 64] * h[(size_t)b * D + t + 64];
    __syncthreads();
    float acc = bp1[t];
    #pragma unroll 4
    for (int i = 0; i < 128; i++) acc += z[i] * Wp1[(size_t)i * 64 + t];
    acc = acc > 0.f ? acc : 0.2f * acc;
    float part = acc * Wp2[t];
    #pragma unroll
    for (int o = 32; o > 0; o >>= 1) part += __shfl_down(part, o);
    if (t == 0) out[p] = part + bp2[0];
}

extern "C" void kernel_launch(void* const* d_in, const int* in_sizes, int n_in,
                              void* d_out, int out_size, void* d_ws, size_t ws_size,
                              hipStream_t stream)
{
    const float* x       = (const float*)d_in[0];
    const int*   src     = (const int*)d_in[1];
    const int*   dst     = (const int*)d_in[2];
    const int*   pos_src = (const int*)d_in[3];
    const int*   pos_dst = (const int*)d_in[4];
    const int*   neg_src = (const int*)d_in[5];
    const int*   neg_dst = (const int*)d_in[6];
    const float* W_in = (const float*)d_in[7];
    const float* b_in = (const float*)d_in[8];
    const float* Wq = (const float*)d_in[9];
    const float* bq = (const float*)d_in[10];
    const float* Wk = (const float*)d_in[11];
    const float* bk = (const float*)d_in[12];
    const float* Wv = (const float*)d_in[13];
    const float* bv = (const float*)d_in[14];
    const float* Wo = (const float*)d_in[15];
    const float* bo = (const float*)d_in[16];
    const float* ln1g = (const float*)d_in[17];
    const float* ln1b = (const float*)d_in[18];
    const float* Wf1 = (const float*)d_in[19];
    const float* bf1 = (const float*)d_in[20];
    const float* Wf2 = (const float*)d_in[21];
    const float* bf2 = (const float*)d_in[22];
    const float* ln2g = (const float*)d_in[23];
    const float* ln2b = (const float*)d_in[24];
    const float* Wp1 = (const float*)d_in[25];
    const float* bp1 = (const float*)d_in[26];
    const float* Wp2 = (const float*)d_in[27];
    const float* bp2 = (const float*)d_in[28];

    float* out = (float*)d_out;
    float* h   = out + 2 * PP;                      // [N,D] f32 residual stream

    // workspace layout (bf16 units from base) — ~81 MB total
    bf16* B    = (bf16*)d_ws;
    bf16* qkvb = B;                                 // [MPAD][384] q|k|v
    bf16* xb   = B;                                 // overlay [MPAD][128]
    bf16* ffb  = B;                                 // overlay [MPAD][256]
    bf16* hb   = B + (size_t)MPAD * 384;            // [MPAD][128]
    float* tmp = (float*)(hb + (size_t)MPAD * 128); // [MPAD][128] f32
    int*  ptr  = (int*)(tmp + (size_t)MPAD * 128);  // [N+1]
    int*  cnt  = ptr + N_NODES + 4;                 // [N]
    int*  ssrc = cnt + N_NODES;                     // [E]
    bf16* wtb  = (bf16*)(ssrc + NE);
    bf16* win_t  = wtb;                             // [128][128]
    bf16* wqkv_t = wtb + 16384;                     // [L][384][128]
    bf16* wo_t   = wtb + 16384 + 98304;             // [L][128][128]
    bf16* wf1_t  = wtb + 16384 + 98304 + 32768;     // [L][256][128]
    bf16* wf2_t  = wtb + 16384 + 98304 + 32768 + 65536; // [L][128][256]
    float* bqkv  = (float*)(wtb + 16384 + 98304 + 32768 + 65536 + 65536); // [L][384]

    auto cdiv = [](int a, int b) { return (a + b - 1) / b; };
    const int GX = MPAD / 128;                      // 391

    // one-time converts
    xb_kernel<<<cdiv(MPAD * IN_F, 256), 256, 0, stream>>>(x, xb);
    bcat_kernel<<<cdiv(NLAYER * 384, 256), 256, 0, stream>>>(bq, bk, bv, bqkv);
    wt_kernel<<<dim3(64, 1),      256, 0, stream>>>(W_in, win_t, 128, 128, 16384);
    wt_kernel<<<dim3(64, NLAYER), 256, 0, stream>>>(Wq, wqkv_t,          128, 128, 49152);
    wt_kernel<<<dim3(64, NLAYER), 256, 0, stream>>>(Wk, wqkv_t + 16384,  128, 128, 49152);
    wt_kernel<<<dim3(64, NLAYER), 256, 0, stream>>>(Wv, wqkv_t + 32768,  128, 128, 49152);
    wt_kernel<<<dim3(64, NLAYER), 256, 0, stream>>>(Wo, wo_t, 128, 128, 16384);
    wt_kernel<<<dim3(128, NLAYER), 256, 0, stream>>>(Wf1, wf1_t, 128, 256, 32768);
    wt_kernel<<<dim3(128, NLAYER), 256, 0, stream>>>(Wf2, wf2_t, 256, 128, 32768);

    // h = x @ W_in + b_in  (f32 into d_out + bf16 shadow)
    gemm_mfma<<<dim3(GX, 1), 256, 0, stream>>>(xb, win_t, b_in, h, hb, N_NODES, 128, 128, 128, 0);

    for (int l = 0; l < NLAYER; l++) {
        const int* sl = src + (size_t)l * NE;
        const int* dl = dst + (size_t)l * NE;

        hipMemsetAsync(cnt, 0, N_NODES * sizeof(int), stream);
        count_kernel<<<cdiv(NE, 256), 256, 0, stream>>>(dl, cnt);
        scan_kernel<<<1, 1024, 0, stream>>>(cnt, ptr);
        hipMemsetAsync(cnt, 0, N_NODES * sizeof(int), stream);
        scatter_kernel<<<cdiv(NE, 256), 256, 0, stream>>>(dl, sl, ptr, cnt, ssrc);

        // fused QKV projection -> qkvb[M][384]
        gemm_mfma<<<dim3(GX, 3), 256, 0, stream>>>(hb, wqkv_t + l * 49152, bqkv + l * 384,
                                                   nullptr, qkvb, N_NODES, 128, 384, 128, 0);

        // fused attention; aggregate written in-place over q section
        attn_fused<<<cdiv(N_NODES, 4), 256, 0, stream>>>(qkvb, ptr, ssrc, qkvb);

        // attn out = agg @ Wo + bo -> tmp ; h = LN(h + tmp)
        gemm_mfma<<<dim3(GX, 1), 256, 0, stream>>>(qkvb, wo_t + l * 16384, bo + l * D,
                                                   tmp, nullptr, N_NODES, 128, 128, 384, 0);
        ln_fused<<<cdiv(N_NODES, 4), 256, 0, stream>>>(h, tmp, ln1g + l * D, ln1b + l * D, h, hb, N_NODES);

        // FFN
        gemm_mfma<<<dim3(GX, 2), 256, 0, stream>>>(hb, wf1_t + l * 32768, bf1 + l * FF,
                                                   nullptr, ffb, N_NODES, 128, 256, 128, 1);
        gemm_mfma<<<dim3(GX, 1), 256, 0, stream>>>(ffb, wf2_t + l * 32768, bf2 + l * D,
                                                   tmp, nullptr, N_NODES, 256, 128, 256, 0);
        ln_fused<<<cdiv(N_NODES, 4), 256, 0, stream>>>(h, tmp, ln2g + l * D, ln2b + l * D, h, hb, N_NODES);
    }

    predict_kernel<<<PP, 64, 0, stream>>>(h, pos_src, pos_dst, Wp1, bp1, Wp2, bp2, out);
    predict_kernel<<<PP, 64, 0, stream>>>(h, neg_src, neg_dst, Wp1, bp1, Wp2, bp2, out + PP);
}

// Round 7
// 539.659 us; speedup vs baseline: 6.6671x; 1.4633x over previous
//
#include <hip/hip_runtime.h>
#include <hip/hip_bf16.h>
#include <math.h>

#define N_NODES 50000
#define NE      800000
#define D       128
#define H       8
#define DH      16
#define NLAYER  2
#define IN_F    128
#define PP      8192
#define FF      256
#define MPAD    50048   // 391 * 128
#define CAP     96      // max in-degree bucket capacity (mean 16, Poisson; P(>=96)~1e-40)

typedef short  bf16x8 __attribute__((ext_vector_type(8)));
typedef float  f32x4  __attribute__((ext_vector_type(4)));
typedef __hip_bfloat16 bf16;

__device__ __forceinline__ float bflo(unsigned int u) { return __uint_as_float(u << 16); }
__device__ __forceinline__ float bfhi(unsigned int u) { return __uint_as_float(u & 0xffff0000u); }

// bucketed CSR build: ssrc[d*CAP + pos] = src(e), cnt[d] = in-degree
__global__ void scatter_kernel(const int* __restrict__ dst, const int* __restrict__ src,
                               int* __restrict__ cnt, int* __restrict__ ssrc) {
    int e = blockIdx.x * blockDim.x + threadIdx.x;
    if (e < NE) {
        int d = dst[e];
        int pos = atomicAdd(&cnt[d], 1);
        if (pos < CAP) ssrc[d * CAP + pos] = src[e];
    }
}

__global__ void xb_kernel(const float* __restrict__ x, bf16* __restrict__ xb) {
    int id = blockIdx.x * blockDim.x + threadIdx.x;
    if (id >= MPAD * IN_F) return;
    int r = id / IN_F;
    xb[id] = __float2bfloat16(r < N_NODES ? x[id] : 0.f);
}

// Wt[obase + n*K + k] = bf16(W[ibase + k*N + n]); grid.y = batch
__global__ void wt_kernel(const float* __restrict__ W, bf16* __restrict__ Wt,
                          int K, int N, int ostride) {
    size_t ibase = (size_t)blockIdx.y * K * N;
    size_t obase = (size_t)blockIdx.y * ostride;
    int id = blockIdx.x * blockDim.x + threadIdx.x;
    if (id >= K * N) return;
    int n = id / K, k = id - n * K;
    Wt[obase + id] = __float2bfloat16(W[ibase + (size_t)k * N + n]);
}

__global__ void bcat_kernel(const float* __restrict__ bq, const float* __restrict__ bk,
                            const float* __restrict__ bv, float* __restrict__ bqkv) {
    int i = blockIdx.x * blockDim.x + threadIdx.x;
    if (i >= NLAYER * 384) return;
    int l = i / 384, c = i - l * 384;
    float v = (c < 128) ? bq[l * 128 + c] : (c < 256 ? bk[l * 128 + c - 128] : bv[l * 128 + c - 256]);
    bqkv[i] = v;
}

// C[M,Nc] = act(A[M,K] @ W + bias); A bf16 [*,lda], Wt bf16 [Nc,K] transposed.
// 128x128 tile, 4 waves (2x2), 4x4 frags of mfma_f32_16x16x32_bf16, XOR-swizzled LDS.
__global__ __launch_bounds__(256) void gemm_mfma(
    const bf16* __restrict__ A, const bf16* __restrict__ Wt,
    const float* __restrict__ bias,
    float* __restrict__ Cf, bf16* __restrict__ Cb,
    int Mvalid, int K, int Nc, int lda, int relu)
{
    __shared__ float4 As4[1024];
    __shared__ float4 Bs4[1024];
    char* As = (char*)As4;
    char* Bs = (char*)Bs4;
    const int t = threadIdx.x;
    const int wave = t >> 6, lane = t & 63;
    const int wr = wave >> 1, wc = wave & 1;
    const int r0 = blockIdx.x * 128, c0 = blockIdx.y * 128;

    f32x4 acc[4][4] = {};

    const int lrow   = t >> 3;
    const int lcol16 = (t & 7) * 16;

    for (int k0 = 0; k0 < K; k0 += 64) {
        #pragma unroll
        for (int p = 0; p < 4; p++) {
            int row = p * 32 + lrow;
            float4 av = *(const float4*)((const char*)(A  + (size_t)(r0 + row) * lda + k0) + lcol16);
            float4 bv = *(const float4*)((const char*)(Wt + (size_t)(c0 + row) * K + k0) + lcol16);
            int sw = lcol16 ^ ((row & 7) << 4);
            *(float4*)(As + row * 128 + sw) = av;
            *(float4*)(Bs + row * 128 + sw) = bv;
        }
        __syncthreads();
        #pragma unroll
        for (int kk = 0; kk < 2; kk++) {
            bf16x8 af[4], bfr[4];
            int kbyte = kk * 64 + (lane >> 4) * 16;
            #pragma unroll
            for (int m = 0; m < 4; m++) {
                int rowa = wr * 64 + m * 16 + (lane & 15);
                af[m]  = *(const bf16x8*)(As + rowa * 128 + (kbyte ^ ((rowa & 7) << 4)));
                int rowb = wc * 64 + m * 16 + (lane & 15);
                bfr[m] = *(const bf16x8*)(Bs + rowb * 128 + (kbyte ^ ((rowb & 7) << 4)));
            }
            #pragma unroll
            for (int m = 0; m < 4; m++)
                #pragma unroll
                for (int n = 0; n < 4; n++)
                    acc[m][n] = __builtin_amdgcn_mfma_f32_16x16x32_bf16(af[m], bfr[n], acc[m][n], 0, 0, 0);
        }
        __syncthreads();
    }

    const int colbase = c0 + wc * 64 + (lane & 15);
    const int rowbase = r0 + wr * 64 + ((lane >> 4) << 2);
    #pragma unroll
    for (int n = 0; n < 4; n++) {
        int col = colbase + n * 16;
        float bsv = bias[col];
        #pragma unroll
        for (int m = 0; m < 4; m++) {
            #pragma unroll
            for (int i = 0; i < 4; i++) {
                int row = rowbase + m * 16 + i;
                if (row < Mvalid) {
                    float v = acc[m][n][i] + bsv;
                    if (relu) v = fmaxf(v, 0.f);
                    if (Cf) Cf[(size_t)row * Nc + col] = v;
                    if (Cb) Cb[(size_t)row * Nc + col] = __float2bfloat16(v);
                }
            }
        }
    }
}

// Fused single-pass attention on qkv[M][384] (q|k|v). One wave per dst node.
// lane = slot*8 + h: lane owns full 16-dim head h for edges slot, slot+8, ...
// Bucketed edge list: ssrc[d*CAP + i], degree = cnt[d].
__global__ __launch_bounds__(256) void attn_fused(
    const bf16* __restrict__ qkv,
    const int* __restrict__ cnt, const int* __restrict__ ssrc,
    bf16* __restrict__ aggout)
{
    int wid = threadIdx.x >> 6, lane = threadIdx.x & 63;
    int d = blockIdx.x * 4 + wid;
    if (d >= N_NODES) return;
    int slot = lane >> 3, h = lane & 7;

    const unsigned int* qr = (const unsigned int*)(qkv + (size_t)d * 384 + h * DH);
    float qf[16];
    {
        uint4 q0 = *(const uint4*)(qr);
        uint4 q1 = *(const uint4*)(qr + 4);
        qf[0]=bflo(q0.x); qf[1]=bfhi(q0.x); qf[2]=bflo(q0.y); qf[3]=bfhi(q0.y);
        qf[4]=bflo(q0.z); qf[5]=bfhi(q0.z); qf[6]=bflo(q0.w); qf[7]=bfhi(q0.w);
        qf[8]=bflo(q1.x); qf[9]=bfhi(q1.x); qf[10]=bflo(q1.y); qf[11]=bfhi(q1.y);
        qf[12]=bflo(q1.z); qf[13]=bfhi(q1.z); qf[14]=bflo(q1.w); qf[15]=bfhi(q1.w);
    }

    int deg = cnt[d];
    if (deg > CAP) deg = CAP;
    const int* bp = ssrc + d * CAP;
    float mx = -INFINITY, den = 0.f;
    float acc[16] = {};

    for (int i = slot; i < deg; i += 8) {
        int s = bp[i];
        const unsigned int* kr = (const unsigned int*)(qkv + (size_t)s * 384 + 128 + h * DH);
        uint4 k0 = *(const uint4*)(kr);
        uint4 k1 = *(const uint4*)(kr + 4);
        uint4 v0 = *(const uint4*)(kr + 64);
        uint4 v1 = *(const uint4*)(kr + 68);
        float p = qf[0]*bflo(k0.x) + qf[1]*bfhi(k0.x)
                + qf[2]*bflo(k0.y) + qf[3]*bfhi(k0.y)
                + qf[4]*bflo(k0.z) + qf[5]*bfhi(k0.z)
                + qf[6]*bflo(k0.w) + qf[7]*bfhi(k0.w)
                + qf[8]*bflo(k1.x) + qf[9]*bfhi(k1.x)
                + qf[10]*bflo(k1.y) + qf[11]*bfhi(k1.y)
                + qf[12]*bflo(k1.z) + qf[13]*bfhi(k1.z)
                + qf[14]*bflo(k1.w) + qf[15]*bfhi(k1.w);
        p *= 0.25f;
        float w;
        if (p > mx) {
            float f = __expf(mx - p);
            den *= f;
            #pragma unroll
            for (int j = 0; j < 16; j++) acc[j] *= f;
            mx = p;
            w = 1.f;
        } else {
            w = __expf(p - mx);
        }
        den += w;
        acc[0]  += w*bflo(v0.x); acc[1]  += w*bfhi(v0.x);
        acc[2]  += w*bflo(v0.y); acc[3]  += w*bfhi(v0.y);
        acc[4]  += w*bflo(v0.z); acc[5]  += w*bfhi(v0.z);
        acc[6]  += w*bflo(v0.w); acc[7]  += w*bfhi(v0.w);
        acc[8]  += w*bflo(v1.x); acc[9]  += w*bfhi(v1.x);
        acc[10] += w*bflo(v1.y); acc[11] += w*bfhi(v1.y);
        acc[12] += w*bflo(v1.z); acc[13] += w*bfhi(v1.z);
        acc[14] += w*bflo(v1.w); acc[15] += w*bfhi(v1.w);
    }

    // merge online states across the 8 slots (lane bits 3..5)
    #pragma unroll
    for (int o = 8; o < 64; o <<= 1) {
        float omx  = __shfl_xor(mx, o);
        float oden = __shfl_xor(den, o);
        float M = fmaxf(mx, omx);
        float fa = (mx  > -INFINITY) ? __expf(mx  - M) : 0.f;
        float fb = (omx > -INFINITY) ? __expf(omx - M) : 0.f;
        den = den * fa + oden * fb;
        #pragma unroll
        for (int j = 0; j < 16; j++) {
            float oa = __shfl_xor(acc[j], o);
            acc[j] = acc[j] * fa + oa * fb;
        }
        mx = M;
    }

    float r = 1.f / (den + 1e-9f);
    float o0 = 0.f, o1 = 0.f;
    #pragma unroll
    for (int j = 0; j < 8; j++) {
        if (slot == j) { o0 = acc[2 * j]; o1 = acc[2 * j + 1]; }
    }
    bf16* op = aggout + (size_t)d * 384 + h * DH + slot * 2;
    op[0] = __float2bfloat16(o0 * r);
    op[1] = __float2bfloat16(o1 * r);
}

// h = LN(a + b)*g + be ; writes f32 out AND bf16 shadow; out may alias a
__global__ void ln_fused(const float* __restrict__ a, const float* __restrict__ b,
                         const float* __restrict__ g, const float* __restrict__ be,
                         float* __restrict__ out, bf16* __restrict__ outb, int M)
{
    int wid = threadIdx.x >> 6, lane = threadIdx.x & 63;
    int row = blockIdx.x * 4 + wid;
    if (row >= M) return;
    const float* ar = a + (size_t)row * D;
    const float* br = b + (size_t)row * D;
    float x1 = ar[lane] + br[lane];
    float x2 = ar[lane + 64] + br[lane + 64];
    float s = x1 + x2;
    #pragma unroll
    for (int o = 32; o > 0; o >>= 1) s += __shfl_xor(s, o);
    float mean = s * (1.f / 128.f);
    float d1 = x1 - mean, d2 = x2 - mean;
    float vs = d1 * d1 + d2 * d2;
    #pragma unroll
    for (int o = 32; o > 0; o >>= 1) vs += __shfl_xor(vs, o);
    float rstd = rsqrtf(vs * (1.f / 128.f) + 1e-5f);
    float o1 = d1 * rstd * g[lane]      + be[lane];
    float o2 = d2 * rstd * g[lane + 64] + be[lane + 64];
    float* orow = out + (size_t)row * D;
    orow[lane] = o1; orow[lane + 64] = o2;
    bf16* obr = outb + (size_t)row * D;
    obr[lane] = __float2bfloat16(o1); obr[lane + 64] = __float2bfloat16(o2);
}

__global__ void predict_kernel(const float* __restrict__ h,
                               const int* __restrict__ ai, const int* __restrict__ bi,
                               const float* __restrict__ Wp1, const float* __restrict__ bp1,
                               const float* __restrict__ Wp2, const float* __restrict__ bp2,
                               float* __restrict__ out)
{
    __shared__ float z[128];
    int p = blockIdx.x;
    int a = ai[p], b = bi[p];
    int t = threadIdx.x;
    z[t]      = h[(size_t)a * D + t]      * h[(size_t)b * D + t];
    z[t + 64] = h[(size_t)a * D + t + 64] * h[(size_t)b * D + t + 64];
    __syncthreads();
    float acc = bp1[t];
    #pragma unroll 4
    for (int i = 0; i < 128; i++) acc += z[i] * Wp1[(size_t)i * 64 + t];
    acc = acc > 0.f ? acc : 0.2f * acc;
    float part = acc * Wp2[t];
    #pragma unroll
    for (int o = 32; o > 0; o >>= 1) part += __shfl_down(part, o);
    if (t == 0) out[p] = part + bp2[0];
}

extern "C" void kernel_launch(void* const* d_in, const int* in_sizes, int n_in,
                              void* d_out, int out_size, void* d_ws, size_t ws_size,
                              hipStream_t stream)
{
    const float* x       = (const float*)d_in[0];
    const int*   src     = (const int*)d_in[1];
    const int*   dst     = (const int*)d_in[2];
    const int*   pos_src = (const int*)d_in[3];
    const int*   pos_dst = (const int*)d_in[4];
    const int*   neg_src = (const int*)d_in[5];
    const int*   neg_dst = (const int*)d_in[6];
    const float* W_in = (const float*)d_in[7];
    const float* b_in = (const float*)d_in[8];
    const float* Wq = (const float*)d_in[9];
    const float* bq = (const float*)d_in[10];
    const float* Wk = (const float*)d_in[11];
    const float* bk = (const float*)d_in[12];
    const float* Wv = (const float*)d_in[13];
    const float* bv = (const float*)d_in[14];
    const float* Wo = (const float*)d_in[15];
    const float* bo = (const float*)d_in[16];
    const float* ln1g = (const float*)d_in[17];
    const float* ln1b = (const float*)d_in[18];
    const float* Wf1 = (const float*)d_in[19];
    const float* bf1 = (const float*)d_in[20];
    const float* Wf2 = (const float*)d_in[21];
    const float* bf2 = (const float*)d_in[22];
    const float* ln2g = (const float*)d_in[23];
    const float* ln2b = (const float*)d_in[24];
    const float* Wp1 = (const float*)d_in[25];
    const float* bp1 = (const float*)d_in[26];
    const float* Wp2 = (const float*)d_in[27];
    const float* bp2 = (const float*)d_in[28];

    float* out = (float*)d_out;
    float* h   = out + 2 * PP;                      // [N,D] f32 residual stream

    // workspace layout (bf16 units from base)
    bf16* B    = (bf16*)d_ws;
    bf16* qkvb = B;                                 // [MPAD][384] q|k|v
    bf16* xb   = B;                                 // overlay [MPAD][128]
    bf16* ffb  = B;                                 // overlay [MPAD][256]
    bf16* hb   = B + (size_t)MPAD * 384;            // [MPAD][128]
    float* tmp = (float*)(hb + (size_t)MPAD * 128); // [MPAD][128] f32
    int*  cnt  = (int*)(tmp + (size_t)MPAD * 128);  // [N]
    int*  ssrc = cnt + N_NODES;                     // [N*CAP]
    bf16* wtb  = (bf16*)(ssrc + (size_t)N_NODES * CAP);
    bf16* win_t  = wtb;                             // [128][128]
    bf16* wqkv_t = wtb + 16384;                     // [L][384][128]
    bf16* wo_t   = wtb + 16384 + 98304;             // [L][128][128]
    bf16* wf1_t  = wtb + 16384 + 98304 + 32768;     // [L][256][128]
    bf16* wf2_t  = wtb + 16384 + 98304 + 32768 + 65536; // [L][128][256]
    float* bqkv  = (float*)(wtb + 16384 + 98304 + 32768 + 65536 + 65536); // [L][384]

    auto cdiv = [](int a, int b) { return (a + b - 1) / b; };
    const int GX = MPAD / 128;                      // 391

    // one-time converts
    xb_kernel<<<cdiv(MPAD * IN_F, 256), 256, 0, stream>>>(x, xb);
    bcat_kernel<<<cdiv(NLAYER * 384, 256), 256, 0, stream>>>(bq, bk, bv, bqkv);
    wt_kernel<<<dim3(64, 1),      256, 0, stream>>>(W_in, win_t, 128, 128, 16384);
    wt_kernel<<<dim3(64, NLAYER), 256, 0, stream>>>(Wq, wqkv_t,          128, 128, 49152);
    wt_kernel<<<dim3(64, NLAYER), 256, 0, stream>>>(Wk, wqkv_t + 16384,  128, 128, 49152);
    wt_kernel<<<dim3(64, NLAYER), 256, 0, stream>>>(Wv, wqkv_t + 32768,  128, 128, 49152);
    wt_kernel<<<dim3(64, NLAYER), 256, 0, stream>>>(Wo, wo_t, 128, 128, 16384);
    wt_kernel<<<dim3(128, NLAYER), 256, 0, stream>>>(Wf1, wf1_t, 128, 256, 32768);
    wt_kernel<<<dim3(128, NLAYER), 256, 0, stream>>>(Wf2, wf2_t, 256, 128, 32768);

    // h = x @ W_in + b_in  (f32 into d_out + bf16 shadow)
    gemm_mfma<<<dim3(GX, 1), 256, 0, stream>>>(xb, win_t, b_in, h, hb, N_NODES, 128, 128, 128, 0);

    for (int l = 0; l < NLAYER; l++) {
        const int* sl = src + (size_t)l * NE;
        const int* dl = dst + (size_t)l * NE;

        // bucketed CSR: memset + scatter (no count, no scan)
        hipMemsetAsync(cnt, 0, N_NODES * sizeof(int), stream);
        scatter_kernel<<<cdiv(NE, 256), 256, 0, stream>>>(dl, sl, cnt, ssrc);

        // fused QKV projection -> qkvb[M][384]
        gemm_mfma<<<dim3(GX, 3), 256, 0, stream>>>(hb, wqkv_t + l * 49152, bqkv + l * 384,
                                                   nullptr, qkvb, N_NODES, 128, 384, 128, 0);

        // fused attention; aggregate written in-place over q section
        attn_fused<<<cdiv(N_NODES, 4), 256, 0, stream>>>(qkvb, cnt, ssrc, qkvb);

        // attn out = agg @ Wo + bo -> tmp ; h = LN(h + tmp)
        gemm_mfma<<<dim3(GX, 1), 256, 0, stream>>>(qkvb, wo_t + l * 16384, bo + l * D,
                                                   tmp, nullptr, N_NODES, 128, 128, 384, 0);
        ln_fused<<<cdiv(N_NODES, 4), 256, 0, stream>>>(h, tmp, ln1g + l * D, ln1b + l * D, h, hb, N_NODES);

        // FFN
        gemm_mfma<<<dim3(GX, 2), 256, 0, stream>>>(hb, wf1_t + l * 32768, bf1 + l * FF,
                                                   nullptr, ffb, N_NODES, 128, 256, 128, 1);
        gemm_mfma<<<dim3(GX, 1), 256, 0, stream>>>(ffb, wf2_t + l * 32768, bf2 + l * D,
                                                   tmp, nullptr, N_NODES, 256, 128, 256, 0);
        ln_fused<<<cdiv(N_NODES, 4), 256, 0, stream>>>(h, tmp, ln2g + l * D, ln2b + l * D, h, hb, N_NODES);
    }

    predict_kernel<<<PP, 64, 0, stream>>>(h, pos_src, pos_dst, Wp1, bp1, Wp2, bp2, out);
    predict_kernel<<<PP, 64, 0, stream>>>(h, neg_src, neg_dst, Wp1, bp1, Wp2, bp2, out + PP);
}

// Round 8
// 496.894 us; speedup vs baseline: 7.2409x; 1.0861x over previous
//
#include <hip/hip_runtime.h>
#include <hip/hip_bf16.h>
#include <math.h>

#define N_NODES 50000
#define NE      800000
#define D       128
#define H       8
#define DH      16
#define NLAYER  2
#define IN_F    128
#define PP      8192
#define FF      256
#define MPAD    50048   // 391 * 128 = 782 * 64
#define CAP     96      // bucket capacity (mean deg 16, Poisson; P(>=96)~1e-40)

typedef short  bf16x8 __attribute__((ext_vector_type(8)));
typedef float  f32x4  __attribute__((ext_vector_type(4)));
typedef __hip_bfloat16 bf16;

__device__ __forceinline__ float bflo(unsigned int u) { return __uint_as_float(u << 16); }
__device__ __forceinline__ float bfhi(unsigned int u) { return __uint_as_float(u & 0xffff0000u); }

// bucketed CSR build for BOTH layers: ssrc[l][d*CAP + pos] = src(e)
__global__ void scatter_kernel(const int* __restrict__ dst, const int* __restrict__ src,
                               int* __restrict__ cnt, int* __restrict__ ssrc) {
    int e = blockIdx.x * blockDim.x + threadIdx.x;
    int l = blockIdx.y;
    if (e < NE) {
        int d = dst[(size_t)l * NE + e];
        int pos = atomicAdd(&cnt[l * N_NODES + d], 1);
        if (pos < CAP) ssrc[(size_t)l * N_NODES * CAP + d * CAP + pos] = src[(size_t)l * NE + e];
    }
}

__global__ void xb_kernel(const float* __restrict__ x, bf16* __restrict__ xb) {
    int id = blockIdx.x * blockDim.x + threadIdx.x;
    if (id >= MPAD * IN_F) return;
    int r = id / IN_F;
    xb[id] = __float2bfloat16(r < N_NODES ? x[id] : 0.f);
}

// Wt[obase + n*K + k] = bf16(W[ibase + k*N + n]); grid.y = batch
__global__ void wt_kernel(const float* __restrict__ W, bf16* __restrict__ Wt,
                          int K, int N, int ostride) {
    size_t ibase = (size_t)blockIdx.y * K * N;
    size_t obase = (size_t)blockIdx.y * ostride;
    int id = blockIdx.x * blockDim.x + threadIdx.x;
    if (id >= K * N) return;
    int n = id / K, k = id - n * K;
    Wt[obase + id] = __float2bfloat16(W[ibase + (size_t)k * N + n]);
}

__global__ void bcat_kernel(const float* __restrict__ bq, const float* __restrict__ bk,
                            const float* __restrict__ bv, float* __restrict__ bqkv) {
    int i = blockIdx.x * blockDim.x + threadIdx.x;
    if (i >= NLAYER * 384) return;
    int l = i / 384, c = i - l * 384;
    float v = (c < 128) ? bq[l * 128 + c] : (c < 256 ? bk[l * 128 + c - 128] : bv[l * 128 + c - 256]);
    bqkv[i] = v;
}

// C[M,Nc] = act(A[M,K] @ W + bias); A bf16 [*,lda], Wt bf16 [Nc,K] transposed.
// 128x128 tile, 4 waves (2x2), 4x4 frags of mfma_f32_16x16x32_bf16, XOR-swizzled LDS.
__global__ __launch_bounds__(256) void gemm_mfma(
    const bf16* __restrict__ A, const bf16* __restrict__ Wt,
    const float* __restrict__ bias,
    float* __restrict__ Cf, bf16* __restrict__ Cb,
    int Mvalid, int K, int Nc, int lda, int relu)
{
    __shared__ float4 As4[1024];
    __shared__ float4 Bs4[1024];
    char* As = (char*)As4;
    char* Bs = (char*)Bs4;
    const int t = threadIdx.x;
    const int wave = t >> 6, lane = t & 63;
    const int wr = wave >> 1, wc = wave & 1;
    const int r0 = blockIdx.x * 128, c0 = blockIdx.y * 128;

    f32x4 acc[4][4] = {};

    const int lrow   = t >> 3;
    const int lcol16 = (t & 7) * 16;

    for (int k0 = 0; k0 < K; k0 += 64) {
        #pragma unroll
        for (int p = 0; p < 4; p++) {
            int row = p * 32 + lrow;
            float4 av = *(const float4*)((const char*)(A  + (size_t)(r0 + row) * lda + k0) + lcol16);
            float4 bv = *(const float4*)((const char*)(Wt + (size_t)(c0 + row) * K + k0) + lcol16);
            int sw = lcol16 ^ ((row & 7) << 4);
            *(float4*)(As + row * 128 + sw) = av;
            *(float4*)(Bs + row * 128 + sw) = bv;
        }
        __syncthreads();
        #pragma unroll
        for (int kk = 0; kk < 2; kk++) {
            bf16x8 af[4], bfr[4];
            int kbyte = kk * 64 + (lane >> 4) * 16;
            #pragma unroll
            for (int m = 0; m < 4; m++) {
                int rowa = wr * 64 + m * 16 + (lane & 15);
                af[m]  = *(const bf16x8*)(As + rowa * 128 + (kbyte ^ ((rowa & 7) << 4)));
                int rowb = wc * 64 + m * 16 + (lane & 15);
                bfr[m] = *(const bf16x8*)(Bs + rowb * 128 + (kbyte ^ ((rowb & 7) << 4)));
            }
            #pragma unroll
            for (int m = 0; m < 4; m++)
                #pragma unroll
                for (int n = 0; n < 4; n++)
                    acc[m][n] = __builtin_amdgcn_mfma_f32_16x16x32_bf16(af[m], bfr[n], acc[m][n], 0, 0, 0);
        }
        __syncthreads();
    }

    const int colbase = c0 + wc * 64 + (lane & 15);
    const int rowbase = r0 + wr * 64 + ((lane >> 4) << 2);
    #pragma unroll
    for (int n = 0; n < 4; n++) {
        int col = colbase + n * 16;
        float bsv = bias[col];
        #pragma unroll
        for (int m = 0; m < 4; m++) {
            #pragma unroll
            for (int i = 0; i < 4; i++) {
                int row = rowbase + m * 16 + i;
                if (row < Mvalid) {
                    float v = acc[m][n][i] + bsv;
                    if (relu) v = fmaxf(v, 0.f);
                    if (Cf) Cf[(size_t)row * Nc + col] = v;
                    if (Cb) Cb[(size_t)row * Nc + col] = __float2bfloat16(v);
                }
            }
        }
    }
}

// Fused GEMM(Nc=128) + bias + residual + LayerNorm + dual-write (f32 h, bf16 hb).
// 64-row tile, 4 waves: wave w owns 16 FULL rows (8 col-frags) -> LN is wave-local
// (row sums via 4 shfl_xor within 16-lane groups).
__global__ __launch_bounds__(256) void gemm_ln(
    const bf16* __restrict__ A, const bf16* __restrict__ Wt,
    const float* __restrict__ bias, const float* __restrict__ g,
    const float* __restrict__ be,
    float* __restrict__ h, bf16* __restrict__ hb,
    int K, int lda)
{
    __shared__ float4 As4[512];    // 64 rows x 128B
    __shared__ float4 Bs4[1024];   // 128 rows x 128B
    char* As = (char*)As4;
    char* Bs = (char*)Bs4;
    const int t = threadIdx.x;
    const int w = t >> 6, lane = t & 63;
    const int r0 = blockIdx.x * 64;

    f32x4 acc[8] = {};

    for (int k0 = 0; k0 < K; k0 += 64) {
        {   // stage A: 64 rows x 128B, 4 threads/row x 32B
            int row = t >> 2;
            int c16 = (t & 3) * 32;
            const char* ap = (const char*)(A + (size_t)(r0 + row) * lda + k0);
            float4 a0 = *(const float4*)(ap + c16);
            float4 a1 = *(const float4*)(ap + c16 + 16);
            *(float4*)(As + row * 128 + ((c16)      ^ ((row & 7) << 4))) = a0;
            *(float4*)(As + row * 128 + ((c16 + 16) ^ ((row & 7) << 4))) = a1;
        }
        {   // stage B: 128 rows x 128B, 2 threads/row x 64B
            int row = t >> 1;
            int c16 = (t & 1) * 64;
            const char* bp = (const char*)(Wt + (size_t)row * K + k0);
            #pragma unroll
            for (int j = 0; j < 4; j++) {
                float4 b = *(const float4*)(bp + c16 + j * 16);
                *(float4*)(Bs + row * 128 + ((c16 + j * 16) ^ ((row & 7) << 4))) = b;
            }
        }
        __syncthreads();
        #pragma unroll
        for (int kk = 0; kk < 2; kk++) {
            int kbyte = kk * 64 + (lane >> 4) * 16;
            int rowa = w * 16 + (lane & 15);
            bf16x8 af = *(const bf16x8*)(As + rowa * 128 + (kbyte ^ ((rowa & 7) << 4)));
            #pragma unroll
            for (int n = 0; n < 8; n++) {
                int rowb = n * 16 + (lane & 15);
                bf16x8 bf8 = *(const bf16x8*)(Bs + rowb * 128 + (kbyte ^ ((rowb & 7) << 4)));
                acc[n] = __builtin_amdgcn_mfma_f32_16x16x32_bf16(af, bf8, acc[n], 0, 0, 0);
            }
        }
        __syncthreads();
    }

    const int sub = lane >> 4;       // 0..3
    const int c   = lane & 15;
    float bsv[8], gv[8], bev[8];
    #pragma unroll
    for (int n = 0; n < 8; n++) {
        int col = n * 16 + c;
        bsv[n] = bias[col]; gv[n] = g[col]; bev[n] = be[col];
    }
    #pragma unroll
    for (int i = 0; i < 4; i++) {
        int row = r0 + w * 16 + sub * 4 + i;
        bool ok = row < N_NODES;
        float x[8];
        float s = 0.f;
        #pragma unroll
        for (int n = 0; n < 8; n++) {
            float res = ok ? h[(size_t)row * D + n * 16 + c] : 0.f;
            x[n] = res + acc[n][i] + bsv[n];
            s += x[n];
        }
        s += __shfl_xor(s, 1); s += __shfl_xor(s, 2);
        s += __shfl_xor(s, 4); s += __shfl_xor(s, 8);
        float mean = s * (1.f / 128.f);
        float v = 0.f;
        #pragma unroll
        for (int n = 0; n < 8; n++) { float dd = x[n] - mean; v += dd * dd; }
        v += __shfl_xor(v, 1); v += __shfl_xor(v, 2);
        v += __shfl_xor(v, 4); v += __shfl_xor(v, 8);
        float rstd = rsqrtf(v * (1.f / 128.f) + 1e-5f);
        if (ok) {
            #pragma unroll
            for (int n = 0; n < 8; n++) {
                float o = (x[n] - mean) * rstd * gv[n] + bev[n];
                h [(size_t)row * D + n * 16 + c] = o;
                hb[(size_t)row * D + n * 16 + c] = __float2bfloat16(o);
            }
        }
    }
}

// Fused single-pass attention on qkv[M][384]. One wave per dst node.
// lane = slot*8 + h: lane owns full 16-dim head h for edges slot, slot+8, ...
__global__ __launch_bounds__(256) void attn_fused(
    const bf16* __restrict__ qkv,
    const int* __restrict__ cnt, const int* __restrict__ ssrc,
    bf16* __restrict__ aggout)
{
    int wid = threadIdx.x >> 6, lane = threadIdx.x & 63;
    int d = blockIdx.x * 4 + wid;
    if (d >= N_NODES) return;
    int slot = lane >> 3, h = lane & 7;

    const unsigned int* qr = (const unsigned int*)(qkv + (size_t)d * 384 + h * DH);
    float qf[16];
    {
        uint4 q0 = *(const uint4*)(qr);
        uint4 q1 = *(const uint4*)(qr + 4);
        qf[0]=bflo(q0.x); qf[1]=bfhi(q0.x); qf[2]=bflo(q0.y); qf[3]=bfhi(q0.y);
        qf[4]=bflo(q0.z); qf[5]=bfhi(q0.z); qf[6]=bflo(q0.w); qf[7]=bfhi(q0.w);
        qf[8]=bflo(q1.x); qf[9]=bfhi(q1.x); qf[10]=bflo(q1.y); qf[11]=bfhi(q1.y);
        qf[12]=bflo(q1.z); qf[13]=bfhi(q1.z); qf[14]=bflo(q1.w); qf[15]=bfhi(q1.w);
    }

    int deg = cnt[d];
    if (deg > CAP) deg = CAP;
    const int* bp = ssrc + (size_t)d * CAP;
    float mx = -INFINITY, den = 0.f;
    float acc[16] = {};

    for (int i = slot; i < deg; i += 8) {
        int s = bp[i];
        const unsigned int* kr = (const unsigned int*)(qkv + (size_t)s * 384 + 128 + h * DH);
        uint4 k0 = *(const uint4*)(kr);
        uint4 k1 = *(const uint4*)(kr + 4);
        uint4 v0 = *(const uint4*)(kr + 64);
        uint4 v1 = *(const uint4*)(kr + 68);
        float p = qf[0]*bflo(k0.x) + qf[1]*bfhi(k0.x)
                + qf[2]*bflo(k0.y) + qf[3]*bfhi(k0.y)
                + qf[4]*bflo(k0.z) + qf[5]*bfhi(k0.z)
                + qf[6]*bflo(k0.w) + qf[7]*bfhi(k0.w)
                + qf[8]*bflo(k1.x) + qf[9]*bfhi(k1.x)
                + qf[10]*bflo(k1.y) + qf[11]*bfhi(k1.y)
                + qf[12]*bflo(k1.z) + qf[13]*bfhi(k1.z)
                + qf[14]*bflo(k1.w) + qf[15]*bfhi(k1.w);
        p *= 0.25f;
        float w;
        if (p > mx) {
            float f = __expf(mx - p);
            den *= f;
            #pragma unroll
            for (int j = 0; j < 16; j++) acc[j] *= f;
            mx = p;
            w = 1.f;
        } else {
            w = __expf(p - mx);
        }
        den += w;
        acc[0]  += w*bflo(v0.x); acc[1]  += w*bfhi(v0.x);
        acc[2]  += w*bflo(v0.y); acc[3]  += w*bfhi(v0.y);
        acc[4]  += w*bflo(v0.z); acc[5]  += w*bfhi(v0.z);
        acc[6]  += w*bflo(v0.w); acc[7]  += w*bfhi(v0.w);
        acc[8]  += w*bflo(v1.x); acc[9]  += w*bfhi(v1.x);
        acc[10] += w*bflo(v1.y); acc[11] += w*bfhi(v1.y);
        acc[12] += w*bflo(v1.z); acc[13] += w*bfhi(v1.z);
        acc[14] += w*bflo(v1.w); acc[15] += w*bfhi(v1.w);
    }

    #pragma unroll
    for (int o = 8; o < 64; o <<= 1) {
        float omx  = __shfl_xor(mx, o);
        float oden = __shfl_xor(den, o);
        float M = fmaxf(mx, omx);
        float fa = (mx  > -INFINITY) ? __expf(mx  - M) : 0.f;
        float fb = (omx > -INFINITY) ? __expf(omx - M) : 0.f;
        den = den * fa + oden * fb;
        #pragma unroll
        for (int j = 0; j < 16; j++) {
            float oa = __shfl_xor(acc[j], o);
            acc[j] = acc[j] * fa + oa * fb;
        }
        mx = M;
    }

    float r = 1.f / (den + 1e-9f);
    float o0 = 0.f, o1 = 0.f;
    #pragma unroll
    for (int j = 0; j < 8; j++) {
        if (slot == j) { o0 = acc[2 * j]; o1 = acc[2 * j + 1]; }
    }
    bf16* op = aggout + (size_t)d * 384 + h * DH + slot * 2;
    op[0] = __float2bfloat16(o0 * r);
    op[1] = __float2bfloat16(o1 * r);
}

// merged pos+neg predictor: block p < PP -> pos, else neg
__global__ void predict_kernel(const float* __restrict__ h,
                               const int* __restrict__ ps, const int* __restrict__ pd,
                               const int* __restrict__ ns, const int* __restrict__ nd,
                               const float* __restrict__ Wp1, const float* __restrict__ bp1,
                               const float* __restrict__ Wp2, const float* __restrict__ bp2,
                               float* __restrict__ out)
{
    __shared__ float z[128];
    int p = blockIdx.x;
    int a, b;
    if (p < PP) { a = ps[p]; b = pd[p]; }
    else        { a = ns[p - PP]; b = nd[p - PP]; }
    int t = threadIdx.x;
    z[t]      = h[(size_t)a * D + t]      * h[(size_t)b * D + t];
    z[t + 64] = h[(size_t)a * D + t + 64] * h[(size_t)b * D + t + 64];
    __syncthreads();
    float acc = bp1[t];
    #pragma unroll 4
    for (int i = 0; i < 128; i++) acc += z[i] * Wp1[(size_t)i * 64 + t];
    acc = acc > 0.f ? acc : 0.2f * acc;
    float part = acc * Wp2[t];
    #pragma unroll
    for (int o = 32; o > 0; o >>= 1) part += __shfl_down(part, o);
    if (t == 0) out[p] = part + bp2[0];
}

extern "C" void kernel_launch(void* const* d_in, const int* in_sizes, int n_in,
                              void* d_out, int out_size, void* d_ws, size_t ws_size,
                              hipStream_t stream)
{
    const float* x       = (const float*)d_in[0];
    const int*   src     = (const int*)d_in[1];
    const int*   dst     = (const int*)d_in[2];
    const int*   pos_src = (const int*)d_in[3];
    const int*   pos_dst = (const int*)d_in[4];
    const int*   neg_src = (const int*)d_in[5];
    const int*   neg_dst = (const int*)d_in[6];
    const float* W_in = (const float*)d_in[7];
    const float* b_in = (const float*)d_in[8];
    const float* Wq = (const float*)d_in[9];
    const float* bq = (const float*)d_in[10];
    const float* Wk = (const float*)d_in[11];
    const float* bk = (const float*)d_in[12];
    const float* Wv = (const float*)d_in[13];
    const float* bv = (const float*)d_in[14];
    const float* Wo = (const float*)d_in[15];
    const float* bo = (const float*)d_in[16];
    const float* ln1g = (const float*)d_in[17];
    const float* ln1b = (const float*)d_in[18];
    const float* Wf1 = (const float*)d_in[19];
    const float* bf1 = (const float*)d_in[20];
    const float* Wf2 = (const float*)d_in[21];
    const float* bf2 = (const float*)d_in[22];
    const float* ln2g = (const float*)d_in[23];
    const float* ln2b = (const float*)d_in[24];
    const float* Wp1 = (const float*)d_in[25];
    const float* bp1 = (const float*)d_in[26];
    const float* Wp2 = (const float*)d_in[27];
    const float* bp2 = (const float*)d_in[28];

    float* out = (float*)d_out;
    float* h   = out + 2 * PP;                      // [N,D] f32 residual stream

    // workspace layout
    bf16* B    = (bf16*)d_ws;
    bf16* qkvb = B;                                 // [MPAD][384] q|k|v
    bf16* xb   = B;                                 // overlay [MPAD][128]
    bf16* ffb  = B;                                 // overlay [MPAD][256]
    bf16* hb   = B + (size_t)MPAD * 384;            // [MPAD][128]
    int*  cnt  = (int*)(hb + (size_t)MPAD * 128);   // [2][N]
    int*  ssrc = cnt + 2 * N_NODES;                 // [2][N*CAP]
    bf16* wtb  = (bf16*)(ssrc + (size_t)2 * N_NODES * CAP);
    bf16* win_t  = wtb;                             // [128][128]
    bf16* wqkv_t = wtb + 16384;                     // [L][384][128]
    bf16* wo_t   = wtb + 16384 + 98304;             // [L][128][128]
    bf16* wf1_t  = wtb + 16384 + 98304 + 32768;     // [L][256][128]
    bf16* wf2_t  = wtb + 16384 + 98304 + 32768 + 65536; // [L][128][256]
    float* bqkv  = (float*)(wtb + 16384 + 98304 + 32768 + 65536 + 65536); // [L][384]

    auto cdiv = [](int a, int b) { return (a + b - 1) / b; };
    const int GX = MPAD / 128;                      // 391
    const int GL = MPAD / 64;                       // 782

    // one-time converts
    xb_kernel<<<cdiv(MPAD * IN_F, 256), 256, 0, stream>>>(x, xb);
    bcat_kernel<<<cdiv(NLAYER * 384, 256), 256, 0, stream>>>(bq, bk, bv, bqkv);
    wt_kernel<<<dim3(64, 1),      256, 0, stream>>>(W_in, win_t, 128, 128, 16384);
    wt_kernel<<<dim3(64, NLAYER), 256, 0, stream>>>(Wq, wqkv_t,          128, 128, 49152);
    wt_kernel<<<dim3(64, NLAYER), 256, 0, stream>>>(Wk, wqkv_t + 16384,  128, 128, 49152);
    wt_kernel<<<dim3(64, NLAYER), 256, 0, stream>>>(Wv, wqkv_t + 32768,  128, 128, 49152);
    wt_kernel<<<dim3(64, NLAYER), 256, 0, stream>>>(Wo, wo_t, 128, 128, 16384);
    wt_kernel<<<dim3(128, NLAYER), 256, 0, stream>>>(Wf1, wf1_t, 128, 256, 32768);
    wt_kernel<<<dim3(128, NLAYER), 256, 0, stream>>>(Wf2, wf2_t, 256, 128, 32768);

    // CSR for both layers (bucketed)
    hipMemsetAsync(cnt, 0, 2 * N_NODES * sizeof(int), stream);
    scatter_kernel<<<dim3(cdiv(NE, 256), 2), 256, 0, stream>>>(dst, src, cnt, ssrc);

    // h = x @ W_in + b_in  (f32 into d_out + bf16 shadow)
    gemm_mfma<<<dim3(GX, 1), 256, 0, stream>>>(xb, win_t, b_in, h, hb, N_NODES, 128, 128, 128, 0);

    for (int l = 0; l < NLAYER; l++) {
        // fused QKV projection -> qkvb[M][384]
        gemm_mfma<<<dim3(GX, 3), 256, 0, stream>>>(hb, wqkv_t + l * 49152, bqkv + l * 384,
                                                   nullptr, qkvb, N_NODES, 128, 384, 128, 0);

        // fused attention; aggregate written in-place over q section
        attn_fused<<<cdiv(N_NODES, 4), 256, 0, stream>>>(qkvb, cnt + l * N_NODES,
                                                         ssrc + (size_t)l * N_NODES * CAP, qkvb);

        // h = LN(h + agg @ Wo + bo)   (fused GEMM+LN)
        gemm_ln<<<GL, 256, 0, stream>>>(qkvb, wo_t + l * 16384, bo + l * D,
                                        ln1g + l * D, ln1b + l * D, h, hb, 128, 384);

        // FFN: ffb = relu(hb @ Wf1 + bf1);  h = LN(h + ffb @ Wf2 + bf2)
        gemm_mfma<<<dim3(GX, 2), 256, 0, stream>>>(hb, wf1_t + l * 32768, bf1 + l * FF,
                                                   nullptr, ffb, N_NODES, 128, 256, 128, 1);
        gemm_ln<<<GL, 256, 0, stream>>>(ffb, wf2_t + l * 32768, bf2 + l * D,
                                        ln2g + l * D, ln2b + l * D, h, hb, 256, 256);
    }

    predict_kernel<<<2 * PP, 64, 0, stream>>>(h, pos_src, pos_dst, neg_src, neg_dst,
                                              Wp1, bp1, Wp2, bp2, out);
}

// Round 9
// 484.167 us; speedup vs baseline: 7.4313x; 1.0263x over previous
//
#include <hip/hip_runtime.h>
#include <hip/hip_bf16.h>
#include <math.h>

#define N_NODES 50000
#define NE      800000
#define D       128
#define H       8
#define DH      16
#define NLAYER  2
#define IN_F    128
#define PP      8192
#define FF      256
#define MPAD    50048   // 391 * 128 = 782 * 64
#define CAP     96      // bucket capacity (mean deg 16, Poisson; P(>=96)~1e-40)

typedef short  bf16x8 __attribute__((ext_vector_type(8)));
typedef float  f32x4  __attribute__((ext_vector_type(4)));
typedef __hip_bfloat16 bf16;
typedef unsigned short u16;

__device__ __forceinline__ float bflo(unsigned int u) { return __uint_as_float(u << 16); }
__device__ __forceinline__ float bfhi(unsigned int u) { return __uint_as_float(u & 0xffff0000u); }

// bucketed CSR build for BOTH layers: ssrc[l][d*CAP + pos] = (u16)src(e)
__global__ void scatter_kernel(const int* __restrict__ dst, const int* __restrict__ src,
                               int* __restrict__ cnt, u16* __restrict__ ssrc) {
    int e = blockIdx.x * blockDim.x + threadIdx.x;
    int l = blockIdx.y;
    if (e < NE) {
        int d = dst[(size_t)l * NE + e];
        int pos = atomicAdd(&cnt[l * N_NODES + d], 1);
        if (pos < CAP) ssrc[((size_t)l * N_NODES + d) * CAP + pos] = (u16)src[(size_t)l * NE + e];
    }
}

__global__ void xb_kernel(const float* __restrict__ x, bf16* __restrict__ xb) {
    int id = blockIdx.x * blockDim.x + threadIdx.x;
    if (id >= MPAD * IN_F) return;
    int r = id / IN_F;
    xb[id] = __float2bfloat16(r < N_NODES ? x[id] : 0.f);
}

// One-shot weight prep: transpose+bf16 all weights, KV-interleaved QKV perm, bias cat.
// Index space: win 16384 | qkv 2*49152 | wo 2*16384 | wf1 2*32768 | wf2 2*32768 | bqkv 2*384
__global__ void prep_kernel(const float* __restrict__ W_in,
                            const float* __restrict__ Wq, const float* __restrict__ Wk,
                            const float* __restrict__ Wv, const float* __restrict__ Wo,
                            const float* __restrict__ Wf1, const float* __restrict__ Wf2,
                            const float* __restrict__ bq, const float* __restrict__ bk,
                            const float* __restrict__ bv,
                            bf16* __restrict__ win_t, bf16* __restrict__ wqkv_t,
                            bf16* __restrict__ wo_t, bf16* __restrict__ wf1_t,
                            bf16* __restrict__ wf2_t, float* __restrict__ bqkv)
{
    int id = blockIdx.x * blockDim.x + threadIdx.x;
    if (id < 16384) {
        int n = id >> 7, k = id & 127;
        win_t[id] = __float2bfloat16(W_in[k * 128 + n]);
        return;
    }
    id -= 16384;
    if (id < NLAYER * 49152) {           // QKV, rows permuted for kv-interleave
        int l = id / 49152, j = id % 49152;
        int r = j >> 7, k = j & 127;
        const float* Ws; int col;
        if (r < 128) { Ws = Wq; col = r; }
        else {
            int u = r - 128, hh = u >> 5, w = u & 31;
            if (w < 16) { Ws = Wk; col = hh * 16 + w; }
            else        { Ws = Wv; col = hh * 16 + w - 16; }
        }
        wqkv_t[(size_t)l * 49152 + j] = __float2bfloat16(Ws[(size_t)l * 16384 + k * 128 + col]);
        return;
    }
    id -= NLAYER * 49152;
    if (id < NLAYER * 16384) {
        int l = id / 16384, j = id % 16384;
        int n = j >> 7, k = j & 127;
        wo_t[id] = __float2bfloat16(Wo[(size_t)l * 16384 + k * 128 + n]);
        return;
    }
    id -= NLAYER * 16384;
    if (id < NLAYER * 32768) {           // wf1: [256][128] from [128][256]
        int l = id / 32768, j = id % 32768;
        int n = j >> 7, k = j & 127;
        wf1_t[id] = __float2bfloat16(Wf1[(size_t)l * 32768 + k * 256 + n]);
        return;
    }
    id -= NLAYER * 32768;
    if (id < NLAYER * 32768) {           // wf2: [128][256] from [256][128]
        int l = id / 32768, j = id % 32768;
        int n = j >> 8, k = j & 255;
        wf2_t[id] = __float2bfloat16(Wf2[(size_t)l * 32768 + k * 128 + n]);
        return;
    }
    id -= NLAYER * 32768;
    if (id < NLAYER * 384) {             // bias cat with same perm
        int l = id / 384, r = id % 384;
        float v;
        if (r < 128) v = bq[l * 128 + r];
        else {
            int u = r - 128, hh = u >> 5, w = u & 31;
            v = (w < 16) ? bk[l * 128 + hh * 16 + w] : bv[l * 128 + hh * 16 + w - 16];
        }
        bqkv[l * 384 + r] = v;
    }
}

// C[M,Nc] = act(A[M,K] @ W + bias); A bf16 [*,lda], Wt bf16 [Nc,K] transposed.
// 128x128 tile, 4 waves (2x2), 4x4 frags of mfma_f32_16x16x32_bf16, XOR-swizzled LDS.
__global__ __launch_bounds__(256) void gemm_mfma(
    const bf16* __restrict__ A, const bf16* __restrict__ Wt,
    const float* __restrict__ bias,
    float* __restrict__ Cf, bf16* __restrict__ Cb,
    int Mvalid, int K, int Nc, int lda, int relu)
{
    __shared__ float4 As4[1024];
    __shared__ float4 Bs4[1024];
    char* As = (char*)As4;
    char* Bs = (char*)Bs4;
    const int t = threadIdx.x;
    const int wave = t >> 6, lane = t & 63;
    const int wr = wave >> 1, wc = wave & 1;
    const int r0 = blockIdx.x * 128, c0 = blockIdx.y * 128;

    f32x4 acc[4][4] = {};

    const int lrow   = t >> 3;
    const int lcol16 = (t & 7) * 16;

    for (int k0 = 0; k0 < K; k0 += 64) {
        #pragma unroll
        for (int p = 0; p < 4; p++) {
            int row = p * 32 + lrow;
            float4 av = *(const float4*)((const char*)(A  + (size_t)(r0 + row) * lda + k0) + lcol16);
            float4 bv = *(const float4*)((const char*)(Wt + (size_t)(c0 + row) * K + k0) + lcol16);
            int sw = lcol16 ^ ((row & 7) << 4);
            *(float4*)(As + row * 128 + sw) = av;
            *(float4*)(Bs + row * 128 + sw) = bv;
        }
        __syncthreads();
        #pragma unroll
        for (int kk = 0; kk < 2; kk++) {
            bf16x8 af[4], bfr[4];
            int kbyte = kk * 64 + (lane >> 4) * 16;
            #pragma unroll
            for (int m = 0; m < 4; m++) {
                int rowa = wr * 64 + m * 16 + (lane & 15);
                af[m]  = *(const bf16x8*)(As + rowa * 128 + (kbyte ^ ((rowa & 7) << 4)));
                int rowb = wc * 64 + m * 16 + (lane & 15);
                bfr[m] = *(const bf16x8*)(Bs + rowb * 128 + (kbyte ^ ((rowb & 7) << 4)));
            }
            #pragma unroll
            for (int m = 0; m < 4; m++)
                #pragma unroll
                for (int n = 0; n < 4; n++)
                    acc[m][n] = __builtin_amdgcn_mfma_f32_16x16x32_bf16(af[m], bfr[n], acc[m][n], 0, 0, 0);
        }
        __syncthreads();
    }

    const int colbase = c0 + wc * 64 + (lane & 15);
    const int rowbase = r0 + wr * 64 + ((lane >> 4) << 2);
    #pragma unroll
    for (int n = 0; n < 4; n++) {
        int col = colbase + n * 16;
        float bsv = bias[col];
        #pragma unroll
        for (int m = 0; m < 4; m++) {
            #pragma unroll
            for (int i = 0; i < 4; i++) {
                int row = rowbase + m * 16 + i;
                if (row < Mvalid) {
                    float v = acc[m][n][i] + bsv;
                    if (relu) v = fmaxf(v, 0.f);
                    if (Cf) Cf[(size_t)row * Nc + col] = v;
                    if (Cb) Cb[(size_t)row * Nc + col] = __float2bfloat16(v);
                }
            }
        }
    }
}

// Fused GEMM(Nc=128) + bias + residual + LayerNorm + dual-write (f32 h, bf16 hb).
__global__ __launch_bounds__(256) void gemm_ln(
    const bf16* __restrict__ A, const bf16* __restrict__ Wt,
    const float* __restrict__ bias, const float* __restrict__ g,
    const float* __restrict__ be,
    float* __restrict__ h, bf16* __restrict__ hb,
    int K, int lda)
{
    __shared__ float4 As4[512];    // 64 rows x 128B
    __shared__ float4 Bs4[1024];   // 128 rows x 128B
    char* As = (char*)As4;
    char* Bs = (char*)Bs4;
    const int t = threadIdx.x;
    const int w = t >> 6, lane = t & 63;
    const int r0 = blockIdx.x * 64;

    f32x4 acc[8] = {};

    for (int k0 = 0; k0 < K; k0 += 64) {
        {
            int row = t >> 2;
            int c16 = (t & 3) * 32;
            const char* ap = (const char*)(A + (size_t)(r0 + row) * lda + k0);
            float4 a0 = *(const float4*)(ap + c16);
            float4 a1 = *(const float4*)(ap + c16 + 16);
            *(float4*)(As + row * 128 + ((c16)      ^ ((row & 7) << 4))) = a0;
            *(float4*)(As + row * 128 + ((c16 + 16) ^ ((row & 7) << 4))) = a1;
        }
        {
            int row = t >> 1;
            int c16 = (t & 1) * 64;
            const char* bp = (const char*)(Wt + (size_t)row * K + k0);
            #pragma unroll
            for (int j = 0; j < 4; j++) {
                float4 b = *(const float4*)(bp + c16 + j * 16);
                *(float4*)(Bs + row * 128 + ((c16 + j * 16) ^ ((row & 7) << 4))) = b;
            }
        }
        __syncthreads();
        #pragma unroll
        for (int kk = 0; kk < 2; kk++) {
            int kbyte = kk * 64 + (lane >> 4) * 16;
            int rowa = w * 16 + (lane & 15);
            bf16x8 af = *(const bf16x8*)(As + rowa * 128 + (kbyte ^ ((rowa & 7) << 4)));
            #pragma unroll
            for (int n = 0; n < 8; n++) {
                int rowb = n * 16 + (lane & 15);
                bf16x8 bf8 = *(const bf16x8*)(Bs + rowb * 128 + (kbyte ^ ((rowb & 7) << 4)));
                acc[n] = __builtin_amdgcn_mfma_f32_16x16x32_bf16(af, bf8, acc[n], 0, 0, 0);
            }
        }
        __syncthreads();
    }

    const int sub = lane >> 4;
    const int c   = lane & 15;
    float bsv[8], gv[8], bev[8];
    #pragma unroll
    for (int n = 0; n < 8; n++) {
        int col = n * 16 + c;
        bsv[n] = bias[col]; gv[n] = g[col]; bev[n] = be[col];
    }
    #pragma unroll
    for (int i = 0; i < 4; i++) {
        int row = r0 + w * 16 + sub * 4 + i;
        bool ok = row < N_NODES;
        float x[8];
        float s = 0.f;
        #pragma unroll
        for (int n = 0; n < 8; n++) {
            float res = ok ? h[(size_t)row * D + n * 16 + c] : 0.f;
            x[n] = res + acc[n][i] + bsv[n];
            s += x[n];
        }
        s += __shfl_xor(s, 1); s += __shfl_xor(s, 2);
        s += __shfl_xor(s, 4); s += __shfl_xor(s, 8);
        float mean = s * (1.f / 128.f);
        float v = 0.f;
        #pragma unroll
        for (int n = 0; n < 8; n++) { float dd = x[n] - mean; v += dd * dd; }
        v += __shfl_xor(v, 1); v += __shfl_xor(v, 2);
        v += __shfl_xor(v, 4); v += __shfl_xor(v, 8);
        float rstd = rsqrtf(v * (1.f / 128.f) + 1e-5f);
        if (ok) {
            #pragma unroll
            for (int n = 0; n < 8; n++) {
                float o = (x[n] - mean) * rstd * gv[n] + bev[n];
                h [(size_t)row * D + n * 16 + c] = o;
                hb[(size_t)row * D + n * 16 + c] = __float2bfloat16(o);
            }
        }
    }
}

// Fused single-pass attention on qkv[M][384] with KV-interleaved layout:
// row = [q(128) | h0:(k16|v16) | h1:(k16|v16) | ...]. One wave per dst node;
// lane = slot*8 + h reads ONE contiguous 64B block per edge.
__global__ __launch_bounds__(256) void attn_fused(
    const bf16* __restrict__ qkv,
    const int* __restrict__ cnt, const u16* __restrict__ ssrc,
    bf16* __restrict__ aggout)
{
    int wid = threadIdx.x >> 6, lane = threadIdx.x & 63;
    int d = blockIdx.x * 4 + wid;
    if (d >= N_NODES) return;
    int slot = lane >> 3, h = lane & 7;

    const unsigned int* qr = (const unsigned int*)(qkv + (size_t)d * 384 + h * DH);
    float qf[16];
    {
        uint4 q0 = *(const uint4*)(qr);
        uint4 q1 = *(const uint4*)(qr + 4);
        qf[0]=bflo(q0.x); qf[1]=bfhi(q0.x); qf[2]=bflo(q0.y); qf[3]=bfhi(q0.y);
        qf[4]=bflo(q0.z); qf[5]=bfhi(q0.z); qf[6]=bflo(q0.w); qf[7]=bfhi(q0.w);
        qf[8]=bflo(q1.x); qf[9]=bfhi(q1.x); qf[10]=bflo(q1.y); qf[11]=bfhi(q1.y);
        qf[12]=bflo(q1.z); qf[13]=bfhi(q1.z); qf[14]=bflo(q1.w); qf[15]=bfhi(q1.w);
    }

    int deg = cnt[d];
    if (deg > CAP) deg = CAP;
    const u16* bp = ssrc + (size_t)d * CAP;
    float mx = -INFINITY, den = 0.f;
    float acc[16] = {};

    for (int i = slot; i < deg; i += 8) {
        int s = bp[i];
        const unsigned int* kvp = (const unsigned int*)(qkv + (size_t)s * 384 + 128 + h * 32);
        uint4 k0 = *(const uint4*)(kvp);
        uint4 k1 = *(const uint4*)(kvp + 4);
        uint4 v0 = *(const uint4*)(kvp + 8);
        uint4 v1 = *(const uint4*)(kvp + 12);
        float p = qf[0]*bflo(k0.x) + qf[1]*bfhi(k0.x)
                + qf[2]*bflo(k0.y) + qf[3]*bfhi(k0.y)
                + qf[4]*bflo(k0.z) + qf[5]*bfhi(k0.z)
                + qf[6]*bflo(k0.w) + qf[7]*bfhi(k0.w)
                + qf[8]*bflo(k1.x) + qf[9]*bfhi(k1.x)
                + qf[10]*bflo(k1.y) + qf[11]*bfhi(k1.y)
                + qf[12]*bflo(k1.z) + qf[13]*bfhi(k1.z)
                + qf[14]*bflo(k1.w) + qf[15]*bfhi(k1.w);
        p *= 0.25f;
        float w;
        if (p > mx) {
            float f = __expf(mx - p);
            den *= f;
            #pragma unroll
            for (int j = 0; j < 16; j++) acc[j] *= f;
            mx = p;
            w = 1.f;
        } else {
            w = __expf(p - mx);
        }
        den += w;
        acc[0]  += w*bflo(v0.x); acc[1]  += w*bfhi(v0.x);
        acc[2]  += w*bflo(v0.y); acc[3]  += w*bfhi(v0.y);
        acc[4]  += w*bflo(v0.z); acc[5]  += w*bfhi(v0.z);
        acc[6]  += w*bflo(v0.w); acc[7]  += w*bfhi(v0.w);
        acc[8]  += w*bflo(v1.x); acc[9]  += w*bfhi(v1.x);
        acc[10] += w*bflo(v1.y); acc[11] += w*bfhi(v1.y);
        acc[12] += w*bflo(v1.z); acc[13] += w*bfhi(v1.z);
        acc[14] += w*bflo(v1.w); acc[15] += w*bfhi(v1.w);
    }

    #pragma unroll
    for (int o = 8; o < 64; o <<= 1) {
        float omx  = __shfl_xor(mx, o);
        float oden = __shfl_xor(den, o);
        float M = fmaxf(mx, omx);
        float fa = (mx  > -INFINITY) ? __expf(mx  - M) : 0.f;
        float fb = (omx > -INFINITY) ? __expf(omx - M) : 0.f;
        den = den * fa + oden * fb;
        #pragma unroll
        for (int j = 0; j < 16; j++) {
            float oa = __shfl_xor(acc[j], o);
            acc[j] = acc[j] * fa + oa * fb;
        }
        mx = M;
    }

    float r = 1.f / (den + 1e-9f);
    float o0 = 0.f, o1 = 0.f;
    #pragma unroll
    for (int j = 0; j < 8; j++) {
        if (slot == j) { o0 = acc[2 * j]; o1 = acc[2 * j + 1]; }
    }
    bf16* op = aggout + (size_t)d * 384 + h * DH + slot * 2;
    op[0] = __float2bfloat16(o0 * r);
    op[1] = __float2bfloat16(o1 * r);
}

// merged pos+neg predictor
__global__ void predict_kernel(const float* __restrict__ h,
                               const int* __restrict__ ps, const int* __restrict__ pd,
                               const int* __restrict__ ns, const int* __restrict__ nd,
                               const float* __restrict__ Wp1, const float* __restrict__ bp1,
                               const float* __restrict__ Wp2, const float* __restrict__ bp2,
                               float* __restrict__ out)
{
    __shared__ float z[128];
    int p = blockIdx.x;
    int a, b;
    if (p < PP) { a = ps[p]; b = pd[p]; }
    else        { a = ns[p - PP]; b = nd[p - PP]; }
    int t = threadIdx.x;
    z[t]      = h[(size_t)a * D + t]      * h[(size_t)b * D + t];
    z[t + 64] = h[(size_t)a * D + t + 64] * h[(size_t)b * D + t + 64];
    __syncthreads();
    float acc = bp1[t];
    #pragma unroll 4
    for (int i = 0; i < 128; i++) acc += z[i] * Wp1[(size_t)i * 64 + t];
    acc = acc > 0.f ? acc : 0.2f * acc;
    float part = acc * Wp2[t];
    #pragma unroll
    for (int o = 32; o > 0; o >>= 1) part += __shfl_down(part, o);
    if (t == 0) out[p] = part + bp2[0];
}

extern "C" void kernel_launch(void* const* d_in, const int* in_sizes, int n_in,
                              void* d_out, int out_size, void* d_ws, size_t ws_size,
                              hipStream_t stream)
{
    const float* x       = (const float*)d_in[0];
    const int*   src     = (const int*)d_in[1];
    const int*   dst     = (const int*)d_in[2];
    const int*   pos_src = (const int*)d_in[3];
    const int*   pos_dst = (const int*)d_in[4];
    const int*   neg_src = (const int*)d_in[5];
    const int*   neg_dst = (const int*)d_in[6];
    const float* W_in = (const float*)d_in[7];
    const float* b_in = (const float*)d_in[8];
    const float* Wq = (const float*)d_in[9];
    const float* bq = (const float*)d_in[10];
    const float* Wk = (const float*)d_in[11];
    const float* bk = (const float*)d_in[12];
    const float* Wv = (const float*)d_in[13];
    const float* bv = (const float*)d_in[14];
    const float* Wo = (const float*)d_in[15];
    const float* bo = (const float*)d_in[16];
    const float* ln1g = (const float*)d_in[17];
    const float* ln1b = (const float*)d_in[18];
    const float* Wf1 = (const float*)d_in[19];
    const float* bf1 = (const float*)d_in[20];
    const float* Wf2 = (const float*)d_in[21];
    const float* bf2 = (const float*)d_in[22];
    const float* ln2g = (const float*)d_in[23];
    const float* ln2b = (const float*)d_in[24];
    const float* Wp1 = (const float*)d_in[25];
    const float* bp1 = (const float*)d_in[26];
    const float* Wp2 = (const float*)d_in[27];
    const float* bp2 = (const float*)d_in[28];

    float* out = (float*)d_out;
    float* h   = out + 2 * PP;                      // [N,D] f32 residual stream

    // workspace layout
    bf16* B    = (bf16*)d_ws;
    bf16* qkvb = B;                                 // [MPAD][384]
    bf16* xb   = B;                                 // overlay [MPAD][128]
    bf16* ffb  = B;                                 // overlay [MPAD][256]
    bf16* hb   = B + (size_t)MPAD * 384;            // [MPAD][128]
    int*  cnt  = (int*)(hb + (size_t)MPAD * 128);   // [2][N]
    u16*  ssrc = (u16*)(cnt + 2 * N_NODES);         // [2][N*CAP] u16
    bf16* wtb  = (bf16*)(ssrc + (size_t)2 * N_NODES * CAP);
    bf16* win_t  = wtb;                             // 16384
    bf16* wqkv_t = wtb + 16384;                     // 2*49152 (kv-interleave perm)
    bf16* wo_t   = wtb + 16384 + 98304;             // 2*16384
    bf16* wf1_t  = wtb + 16384 + 98304 + 32768;     // 2*32768
    bf16* wf2_t  = wtb + 16384 + 98304 + 32768 + 65536; // 2*32768
    float* bqkv  = (float*)(wtb + 16384 + 98304 + 32768 + 65536 + 65536); // [L][384]

    auto cdiv = [](int a, int b) { return (a + b - 1) / b; };
    const int GX = MPAD / 128;                      // 391
    const int GL = MPAD / 64;                       // 782

    // one-time converts (2 launches)
    xb_kernel<<<cdiv(MPAD * IN_F, 256), 256, 0, stream>>>(x, xb);
    prep_kernel<<<1091, 256, 0, stream>>>(W_in, Wq, Wk, Wv, Wo, Wf1, Wf2, bq, bk, bv,
                                          win_t, wqkv_t, wo_t, wf1_t, wf2_t, bqkv);

    // bucketed CSR for both layers
    hipMemsetAsync(cnt, 0, 2 * N_NODES * sizeof(int), stream);
    scatter_kernel<<<dim3(cdiv(NE, 256), 2), 256, 0, stream>>>(dst, src, cnt, ssrc);

    // h = x @ W_in + b_in
    gemm_mfma<<<dim3(GX, 1), 256, 0, stream>>>(xb, win_t, b_in, h, hb, N_NODES, 128, 128, 128, 0);

    for (int l = 0; l < NLAYER; l++) {
        gemm_mfma<<<dim3(GX, 3), 256, 0, stream>>>(hb, wqkv_t + l * 49152, bqkv + l * 384,
                                                   nullptr, qkvb, N_NODES, 128, 384, 128, 0);

        attn_fused<<<cdiv(N_NODES, 4), 256, 0, stream>>>(qkvb, cnt + l * N_NODES,
                                                         ssrc + (size_t)l * N_NODES * CAP, qkvb);

        gemm_ln<<<GL, 256, 0, stream>>>(qkvb, wo_t + l * 16384, bo + l * D,
                                        ln1g + l * D, ln1b + l * D, h, hb, 128, 384);

        gemm_mfma<<<dim3(GX, 2), 256, 0, stream>>>(hb, wf1_t + l * 32768, bf1 + l * FF,
                                                   nullptr, ffb, N_NODES, 128, 256, 128, 1);
        gemm_ln<<<GL, 256, 0, stream>>>(ffb, wf2_t + l * 32768, bf2 + l * D,
                                        ln2g + l * D, ln2b + l * D, h, hb, 256, 256);
    }

    predict_kernel<<<2 * PP, 64, 0, stream>>>(h, pos_src, pos_dst, neg_src, neg_dst,
                                              Wp1, bp1, Wp2, bp2, out);
}

// Round 10
// 400.585 us; speedup vs baseline: 8.9818x; 1.2087x over previous
//
#include <hip/hip_runtime.h>
#include <hip/hip_bf16.h>
#include <math.h>

#define N_NODES 50000
#define NE      800000
#define D       128
#define H       8
#define DH      16
#define NLAYER  2
#define IN_F    128
#define PP      8192
#define FF      256
#define MPAD    50048   // 391 * 128 = 782 * 64
#define CAP     96      // bucket capacity (mean deg 16; P(>=96)~1e-40)
#define NBIN    196     // bins of 256 nodes: bin = d >> 8
#define BCAP    48      // per-chunk per-bin LDS cap (mean 10.4; P(>=48)~3e-16)
#define GCAP    4608    // per-bin global cap (mean 4096, sigma 64; +8 sigma)
#define CHUNK   2048    // edges per phase-1 block

typedef short  bf16x8 __attribute__((ext_vector_type(8)));
typedef float  f32x4  __attribute__((ext_vector_type(4)));
typedef __hip_bfloat16 bf16;
typedef unsigned short u16;
typedef unsigned int   u32;

__device__ __forceinline__ float bflo(u32 u) { return __uint_as_float(u << 16); }
__device__ __forceinline__ float bfhi(u32 u) { return __uint_as_float(u & 0xffff0000u); }

// Phase 1: bin edges by dst>>8 via LDS, flush dense appends to per-bin global arrays.
__global__ __launch_bounds__(256) void bin_kernel(
    const int* __restrict__ dst, const int* __restrict__ src,
    u32* __restrict__ gbin, int* __restrict__ gbin_cnt)
{
    __shared__ u32 ent[NBIN * BCAP];
    __shared__ int bcnt[NBIN];
    const int t = threadIdx.x, l = blockIdx.y;
    const int base = blockIdx.x * CHUNK;
    if (t < NBIN) bcnt[t] = 0;
    __syncthreads();
    #pragma unroll
    for (int j = 0; j < CHUNK / 256; j++) {
        int e = base + j * 256 + t;
        if (e < NE) {
            int d = dst[(size_t)l * NE + e];
            int s = src[(size_t)l * NE + e];
            int bin = d >> 8;
            int slot = atomicAdd(&bcnt[bin], 1);
            if (slot < BCAP) ent[bin * BCAP + slot] = ((u32)s << 16) | (u32)(d & 255);
        }
    }
    __syncthreads();
    if (t < NBIN) {
        int c = bcnt[t]; if (c > BCAP) c = BCAP;
        if (c > 0) {
            int gb = atomicAdd(&gbin_cnt[l * NBIN + t], c);
            u32* gp = gbin + ((size_t)l * NBIN + t) * GCAP;
            for (int i = 0; i < c; i++)
                if (gb + i < GCAP) gp[gb + i] = ent[t * BCAP + i];
        }
    }
}

// Phase 2: per (bin, layer) block expands packed edges into the final CAP-buckets
// using LDS counters; all ssrc writes fall in a 48KB L2-local window. Writes cnt exact.
__global__ __launch_bounds__(256) void expand_kernel(
    const u32* __restrict__ gbin, const int* __restrict__ gbin_cnt,
    int* __restrict__ cnt, u16* __restrict__ ssrc)
{
    __shared__ int lcnt[256];
    const int t = threadIdx.x, b = blockIdx.x, l = blockIdx.y;
    lcnt[t] = 0;
    __syncthreads();
    int n = gbin_cnt[l * NBIN + b]; if (n > GCAP) n = GCAP;
    const u32* gp = gbin + ((size_t)l * NBIN + b) * GCAP;
    for (int i = t; i < n; i += 256) {
        u32 u = gp[i];
        int dl = (int)(u & 255);
        int pos = atomicAdd(&lcnt[dl], 1);
        if (pos < CAP) {
            int d = (b << 8) + dl;
            ssrc[((size_t)l * N_NODES + d) * CAP + pos] = (u16)(u >> 16);
        }
    }
    __syncthreads();
    int d = (b << 8) + t;
    if (d < N_NODES) cnt[l * N_NODES + d] = lcnt[t];
}

__global__ void xb_kernel(const float* __restrict__ x, bf16* __restrict__ xb) {
    int id = blockIdx.x * blockDim.x + threadIdx.x;
    if (id >= MPAD * IN_F) return;
    int r = id / IN_F;
    xb[id] = __float2bfloat16(r < N_NODES ? x[id] : 0.f);
}

// One-shot weight prep: transpose+bf16 all weights, KV-interleaved QKV perm, bias cat.
__global__ void prep_kernel(const float* __restrict__ W_in,
                            const float* __restrict__ Wq, const float* __restrict__ Wk,
                            const float* __restrict__ Wv, const float* __restrict__ Wo,
                            const float* __restrict__ Wf1, const float* __restrict__ Wf2,
                            const float* __restrict__ bq, const float* __restrict__ bk,
                            const float* __restrict__ bv,
                            bf16* __restrict__ win_t, bf16* __restrict__ wqkv_t,
                            bf16* __restrict__ wo_t, bf16* __restrict__ wf1_t,
                            bf16* __restrict__ wf2_t, float* __restrict__ bqkv)
{
    int id = blockIdx.x * blockDim.x + threadIdx.x;
    if (id < 16384) {
        int n = id >> 7, k = id & 127;
        win_t[id] = __float2bfloat16(W_in[k * 128 + n]);
        return;
    }
    id -= 16384;
    if (id < NLAYER * 49152) {           // QKV, rows permuted for kv-interleave
        int l = id / 49152, j = id % 49152;
        int r = j >> 7, k = j & 127;
        const float* Ws; int col;
        if (r < 128) { Ws = Wq; col = r; }
        else {
            int u = r - 128, hh = u >> 5, w = u & 31;
            if (w < 16) { Ws = Wk; col = hh * 16 + w; }
            else        { Ws = Wv; col = hh * 16 + w - 16; }
        }
        wqkv_t[(size_t)l * 49152 + j] = __float2bfloat16(Ws[(size_t)l * 16384 + k * 128 + col]);
        return;
    }
    id -= NLAYER * 49152;
    if (id < NLAYER * 16384) {
        int l = id / 16384, j = id % 16384;
        int n = j >> 7, k = j & 127;
        wo_t[id] = __float2bfloat16(Wo[(size_t)l * 16384 + k * 128 + n]);
        return;
    }
    id -= NLAYER * 16384;
    if (id < NLAYER * 32768) {           // wf1: [256][128] from [128][256]
        int l = id / 32768, j = id % 32768;
        int n = j >> 7, k = j & 127;
        wf1_t[id] = __float2bfloat16(Wf1[(size_t)l * 32768 + k * 256 + n]);
        return;
    }
    id -= NLAYER * 32768;
    if (id < NLAYER * 32768) {           // wf2: [128][256] from [256][128]
        int l = id / 32768, j = id % 32768;
        int n = j >> 8, k = j & 255;
        wf2_t[id] = __float2bfloat16(Wf2[(size_t)l * 32768 + k * 128 + n]);
        return;
    }
    id -= NLAYER * 32768;
    if (id < NLAYER * 384) {             // bias cat with same perm
        int l = id / 384, r = id % 384;
        float v;
        if (r < 128) v = bq[l * 128 + r];
        else {
            int u = r - 128, hh = u >> 5, w = u & 31;
            v = (w < 16) ? bk[l * 128 + hh * 16 + w] : bv[l * 128 + hh * 16 + w - 16];
        }
        bqkv[l * 384 + r] = v;
    }
}

// C[M,Nc] = act(A[M,K] @ W + bias); A bf16 [*,lda], Wt bf16 [Nc,K] transposed.
__global__ __launch_bounds__(256) void gemm_mfma(
    const bf16* __restrict__ A, const bf16* __restrict__ Wt,
    const float* __restrict__ bias,
    float* __restrict__ Cf, bf16* __restrict__ Cb,
    int Mvalid, int K, int Nc, int lda, int relu)
{
    __shared__ float4 As4[1024];
    __shared__ float4 Bs4[1024];
    char* As = (char*)As4;
    char* Bs = (char*)Bs4;
    const int t = threadIdx.x;
    const int wave = t >> 6, lane = t & 63;
    const int wr = wave >> 1, wc = wave & 1;
    const int r0 = blockIdx.x * 128, c0 = blockIdx.y * 128;

    f32x4 acc[4][4] = {};

    const int lrow   = t >> 3;
    const int lcol16 = (t & 7) * 16;

    for (int k0 = 0; k0 < K; k0 += 64) {
        #pragma unroll
        for (int p = 0; p < 4; p++) {
            int row = p * 32 + lrow;
            float4 av = *(const float4*)((const char*)(A  + (size_t)(r0 + row) * lda + k0) + lcol16);
            float4 bv = *(const float4*)((const char*)(Wt + (size_t)(c0 + row) * K + k0) + lcol16);
            int sw = lcol16 ^ ((row & 7) << 4);
            *(float4*)(As + row * 128 + sw) = av;
            *(float4*)(Bs + row * 128 + sw) = bv;
        }
        __syncthreads();
        #pragma unroll
        for (int kk = 0; kk < 2; kk++) {
            bf16x8 af[4], bfr[4];
            int kbyte = kk * 64 + (lane >> 4) * 16;
            #pragma unroll
            for (int m = 0; m < 4; m++) {
                int rowa = wr * 64 + m * 16 + (lane & 15);
                af[m]  = *(const bf16x8*)(As + rowa * 128 + (kbyte ^ ((rowa & 7) << 4)));
                int rowb = wc * 64 + m * 16 + (lane & 15);
                bfr[m] = *(const bf16x8*)(Bs + rowb * 128 + (kbyte ^ ((rowb & 7) << 4)));
            }
            #pragma unroll
            for (int m = 0; m < 4; m++)
                #pragma unroll
                for (int n = 0; n < 4; n++)
                    acc[m][n] = __builtin_amdgcn_mfma_f32_16x16x32_bf16(af[m], bfr[n], acc[m][n], 0, 0, 0);
        }
        __syncthreads();
    }

    const int colbase = c0 + wc * 64 + (lane & 15);
    const int rowbase = r0 + wr * 64 + ((lane >> 4) << 2);
    #pragma unroll
    for (int n = 0; n < 4; n++) {
        int col = colbase + n * 16;
        float bsv = bias[col];
        #pragma unroll
        for (int m = 0; m < 4; m++) {
            #pragma unroll
            for (int i = 0; i < 4; i++) {
                int row = rowbase + m * 16 + i;
                if (row < Mvalid) {
                    float v = acc[m][n][i] + bsv;
                    if (relu) v = fmaxf(v, 0.f);
                    if (Cf) Cf[(size_t)row * Nc + col] = v;
                    if (Cb) Cb[(size_t)row * Nc + col] = __float2bfloat16(v);
                }
            }
        }
    }
}

// Fused GEMM(Nc=128) + bias + residual + LayerNorm + dual-write (f32 h, bf16 hb).
__global__ __launch_bounds__(256) void gemm_ln(
    const bf16* __restrict__ A, const bf16* __restrict__ Wt,
    const float* __restrict__ bias, const float* __restrict__ g,
    const float* __restrict__ be,
    float* __restrict__ h, bf16* __restrict__ hb,
    int K, int lda)
{
    __shared__ float4 As4[512];
    __shared__ float4 Bs4[1024];
    char* As = (char*)As4;
    char* Bs = (char*)Bs4;
    const int t = threadIdx.x;
    const int w = t >> 6, lane = t & 63;
    const int r0 = blockIdx.x * 64;

    f32x4 acc[8] = {};

    for (int k0 = 0; k0 < K; k0 += 64) {
        {
            int row = t >> 2;
            int c16 = (t & 3) * 32;
            const char* ap = (const char*)(A + (size_t)(r0 + row) * lda + k0);
            float4 a0 = *(const float4*)(ap + c16);
            float4 a1 = *(const float4*)(ap + c16 + 16);
            *(float4*)(As + row * 128 + ((c16)      ^ ((row & 7) << 4))) = a0;
            *(float4*)(As + row * 128 + ((c16 + 16) ^ ((row & 7) << 4))) = a1;
        }
        {
            int row = t >> 1;
            int c16 = (t & 1) * 64;
            const char* bp = (const char*)(Wt + (size_t)row * K + k0);
            #pragma unroll
            for (int j = 0; j < 4; j++) {
                float4 b = *(const float4*)(bp + c16 + j * 16);
                *(float4*)(Bs + row * 128 + ((c16 + j * 16) ^ ((row & 7) << 4))) = b;
            }
        }
        __syncthreads();
        #pragma unroll
        for (int kk = 0; kk < 2; kk++) {
            int kbyte = kk * 64 + (lane >> 4) * 16;
            int rowa = w * 16 + (lane & 15);
            bf16x8 af = *(const bf16x8*)(As + rowa * 128 + (kbyte ^ ((rowa & 7) << 4)));
            #pragma unroll
            for (int n = 0; n < 8; n++) {
                int rowb = n * 16 + (lane & 15);
                bf16x8 bf8 = *(const bf16x8*)(Bs + rowb * 128 + (kbyte ^ ((rowb & 7) << 4)));
                acc[n] = __builtin_amdgcn_mfma_f32_16x16x32_bf16(af, bf8, acc[n], 0, 0, 0);
            }
        }
        __syncthreads();
    }

    const int sub = lane >> 4;
    const int c   = lane & 15;
    float bsv[8], gv[8], bev[8];
    #pragma unroll
    for (int n = 0; n < 8; n++) {
        int col = n * 16 + c;
        bsv[n] = bias[col]; gv[n] = g[col]; bev[n] = be[col];
    }
    #pragma unroll
    for (int i = 0; i < 4; i++) {
        int row = r0 + w * 16 + sub * 4 + i;
        bool ok = row < N_NODES;
        float x[8];
        float s = 0.f;
        #pragma unroll
        for (int n = 0; n < 8; n++) {
            float res = ok ? h[(size_t)row * D + n * 16 + c] : 0.f;
            x[n] = res + acc[n][i] + bsv[n];
            s += x[n];
        }
        s += __shfl_xor(s, 1); s += __shfl_xor(s, 2);
        s += __shfl_xor(s, 4); s += __shfl_xor(s, 8);
        float mean = s * (1.f / 128.f);
        float v = 0.f;
        #pragma unroll
        for (int n = 0; n < 8; n++) { float dd = x[n] - mean; v += dd * dd; }
        v += __shfl_xor(v, 1); v += __shfl_xor(v, 2);
        v += __shfl_xor(v, 4); v += __shfl_xor(v, 8);
        float rstd = rsqrtf(v * (1.f / 128.f) + 1e-5f);
        if (ok) {
            #pragma unroll
            for (int n = 0; n < 8; n++) {
                float o = (x[n] - mean) * rstd * gv[n] + bev[n];
                h [(size_t)row * D + n * 16 + c] = o;
                hb[(size_t)row * D + n * 16 + c] = __float2bfloat16(o);
            }
        }
    }
}

// Fused single-pass attention on qkv[M][384] with KV-interleaved layout.
__global__ __launch_bounds__(256) void attn_fused(
    const bf16* __restrict__ qkv,
    const int* __restrict__ cnt, const u16* __restrict__ ssrc,
    bf16* __restrict__ aggout)
{
    int wid = threadIdx.x >> 6, lane = threadIdx.x & 63;
    int d = blockIdx.x * 4 + wid;
    if (d >= N_NODES) return;
    int slot = lane >> 3, h = lane & 7;

    const u32* qr = (const u32*)(qkv + (size_t)d * 384 + h * DH);
    float qf[16];
    {
        uint4 q0 = *(const uint4*)(qr);
        uint4 q1 = *(const uint4*)(qr + 4);
        qf[0]=bflo(q0.x); qf[1]=bfhi(q0.x); qf[2]=bflo(q0.y); qf[3]=bfhi(q0.y);
        qf[4]=bflo(q0.z); qf[5]=bfhi(q0.z); qf[6]=bflo(q0.w); qf[7]=bfhi(q0.w);
        qf[8]=bflo(q1.x); qf[9]=bfhi(q1.x); qf[10]=bflo(q1.y); qf[11]=bfhi(q1.y);
        qf[12]=bflo(q1.z); qf[13]=bfhi(q1.z); qf[14]=bflo(q1.w); qf[15]=bfhi(q1.w);
    }

    int deg = cnt[d];
    if (deg > CAP) deg = CAP;
    const u16* bp = ssrc + (size_t)d * CAP;
    float mx = -INFINITY, den = 0.f;
    float acc[16] = {};

    for (int i = slot; i < deg; i += 8) {
        int s = bp[i];
        const u32* kvp = (const u32*)(qkv + (size_t)s * 384 + 128 + h * 32);
        uint4 k0 = *(const uint4*)(kvp);
        uint4 k1 = *(const uint4*)(kvp + 4);
        uint4 v0 = *(const uint4*)(kvp + 8);
        uint4 v1 = *(const uint4*)(kvp + 12);
        float p = qf[0]*bflo(k0.x) + qf[1]*bfhi(k0.x)
                + qf[2]*bflo(k0.y) + qf[3]*bfhi(k0.y)
                + qf[4]*bflo(k0.z) + qf[5]*bfhi(k0.z)
                + qf[6]*bflo(k0.w) + qf[7]*bfhi(k0.w)
                + qf[8]*bflo(k1.x) + qf[9]*bfhi(k1.x)
                + qf[10]*bflo(k1.y) + qf[11]*bfhi(k1.y)
                + qf[12]*bflo(k1.z) + qf[13]*bfhi(k1.z)
                + qf[14]*bflo(k1.w) + qf[15]*bfhi(k1.w);
        p *= 0.25f;
        float w;
        if (p > mx) {
            float f = __expf(mx - p);
            den *= f;
            #pragma unroll
            for (int j = 0; j < 16; j++) acc[j] *= f;
            mx = p;
            w = 1.f;
        } else {
            w = __expf(p - mx);
        }
        den += w;
        acc[0]  += w*bflo(v0.x); acc[1]  += w*bfhi(v0.x);
        acc[2]  += w*bflo(v0.y); acc[3]  += w*bfhi(v0.y);
        acc[4]  += w*bflo(v0.z); acc[5]  += w*bfhi(v0.z);
        acc[6]  += w*bflo(v0.w); acc[7]  += w*bfhi(v0.w);
        acc[8]  += w*bflo(v1.x); acc[9]  += w*bfhi(v1.x);
        acc[10] += w*bflo(v1.y); acc[11] += w*bfhi(v1.y);
        acc[12] += w*bflo(v1.z); acc[13] += w*bfhi(v1.z);
        acc[14] += w*bflo(v1.w); acc[15] += w*bfhi(v1.w);
    }

    #pragma unroll
    for (int o = 8; o < 64; o <<= 1) {
        float omx  = __shfl_xor(mx, o);
        float oden = __shfl_xor(den, o);
        float M = fmaxf(mx, omx);
        float fa = (mx  > -INFINITY) ? __expf(mx  - M) : 0.f;
        float fb = (omx > -INFINITY) ? __expf(omx - M) : 0.f;
        den = den * fa + oden * fb;
        #pragma unroll
        for (int j = 0; j < 16; j++) {
            float oa = __shfl_xor(acc[j], o);
            acc[j] = acc[j] * fa + oa * fb;
        }
        mx = M;
    }

    float r = 1.f / (den + 1e-9f);
    float o0 = 0.f, o1 = 0.f;
    #pragma unroll
    for (int j = 0; j < 8; j++) {
        if (slot == j) { o0 = acc[2 * j]; o1 = acc[2 * j + 1]; }
    }
    bf16* op = aggout + (size_t)d * 384 + h * DH + slot * 2;
    op[0] = __float2bfloat16(o0 * r);
    op[1] = __float2bfloat16(o1 * r);
}

// merged pos+neg predictor
__global__ void predict_kernel(const float* __restrict__ h,
                               const int* __restrict__ ps, const int* __restrict__ pd,
                               const int* __restrict__ ns, const int* __restrict__ nd,
                               const float* __restrict__ Wp1, const float* __restrict__ bp1,
                               const float* __restrict__ Wp2, const float* __restrict__ bp2,
                               float* __restrict__ out)
{
    __shared__ float z[128];
    int p = blockIdx.x;
    int a, b;
    if (p < PP) { a = ps[p]; b = pd[p]; }
    else        { a = ns[p - PP]; b = nd[p - PP]; }
    int t = threadIdx.x;
    z[t]      = h[(size_t)a * D + t]      * h[(size_t)b * D + t];
    z[t + 64] = h[(size_t)a * D + t + 64] * h[(size_t)b * D + t + 64];
    __syncthreads();
    float acc = bp1[t];
    #pragma unroll 4
    for (int i = 0; i < 128; i++) acc += z[i] * Wp1[(size_t)i * 64 + t];
    acc = acc > 0.f ? acc : 0.2f * acc;
    float part = acc * Wp2[t];
    #pragma unroll
    for (int o = 32; o > 0; o >>= 1) part += __shfl_down(part, o);
    if (t == 0) out[p] = part + bp2[0];
}

extern "C" void kernel_launch(void* const* d_in, const int* in_sizes, int n_in,
                              void* d_out, int out_size, void* d_ws, size_t ws_size,
                              hipStream_t stream)
{
    const float* x       = (const float*)d_in[0];
    const int*   src     = (const int*)d_in[1];
    const int*   dst     = (const int*)d_in[2];
    const int*   pos_src = (const int*)d_in[3];
    const int*   pos_dst = (const int*)d_in[4];
    const int*   neg_src = (const int*)d_in[5];
    const int*   neg_dst = (const int*)d_in[6];
    const float* W_in = (const float*)d_in[7];
    const float* b_in = (const float*)d_in[8];
    const float* Wq = (const float*)d_in[9];
    const float* bq = (const float*)d_in[10];
    const float* Wk = (const float*)d_in[11];
    const float* bk = (const float*)d_in[12];
    const float* Wv = (const float*)d_in[13];
    const float* bv = (const float*)d_in[14];
    const float* Wo = (const float*)d_in[15];
    const float* bo = (const float*)d_in[16];
    const float* ln1g = (const float*)d_in[17];
    const float* ln1b = (const float*)d_in[18];
    const float* Wf1 = (const float*)d_in[19];
    const float* bf1 = (const float*)d_in[20];
    const float* Wf2 = (const float*)d_in[21];
    const float* bf2 = (const float*)d_in[22];
    const float* ln2g = (const float*)d_in[23];
    const float* ln2b = (const float*)d_in[24];
    const float* Wp1 = (const float*)d_in[25];
    const float* bp1 = (const float*)d_in[26];
    const float* Wp2 = (const float*)d_in[27];
    const float* bp2 = (const float*)d_in[28];

    float* out = (float*)d_out;
    float* h   = out + 2 * PP;                      // [N,D] f32 residual stream

    // workspace layout
    bf16* B    = (bf16*)d_ws;
    bf16* qkvb = B;                                 // [MPAD][384]
    bf16* xb   = B;                                 // overlay [MPAD][128]
    bf16* ffb  = B;                                 // overlay [MPAD][256]
    bf16* hb   = B + (size_t)MPAD * 384;            // [MPAD][128]
    int*  cnt  = (int*)(hb + (size_t)MPAD * 128);   // [2][N]
    u16*  ssrc = (u16*)(cnt + 2 * N_NODES);         // [2][N*CAP]
    bf16* wtb  = (bf16*)(ssrc + (size_t)2 * N_NODES * CAP);
    bf16* win_t  = wtb;                             // 16384
    bf16* wqkv_t = wtb + 16384;                     // 2*49152 (kv-interleave perm)
    bf16* wo_t   = wtb + 16384 + 98304;             // 2*16384
    bf16* wf1_t  = wtb + 16384 + 98304 + 32768;     // 2*32768
    bf16* wf2_t  = wtb + 16384 + 98304 + 32768 + 65536; // 2*32768
    float* bqkv  = (float*)(wtb + 16384 + 98304 + 32768 + 65536 + 65536); // [L][384]
    int*  gbin_cnt = (int*)(bqkv + NLAYER * 384);   // [2][NBIN]
    u32*  gbin     = (u32*)(gbin_cnt + 2 * NBIN);   // [2][NBIN][GCAP]

    auto cdiv = [](int a, int b) { return (a + b - 1) / b; };
    const int GX = MPAD / 128;                      // 391
    const int GL = MPAD / 64;                       // 782

    // one-time converts
    xb_kernel<<<cdiv(MPAD * IN_F, 256), 256, 0, stream>>>(x, xb);
    prep_kernel<<<1091, 256, 0, stream>>>(W_in, Wq, Wk, Wv, Wo, Wf1, Wf2, bq, bk, bv,
                                          win_t, wqkv_t, wo_t, wf1_t, wf2_t, bqkv);

    // CSR build: bin -> expand (dense writes, no global cnt atomics)
    hipMemsetAsync(gbin_cnt, 0, 2 * NBIN * sizeof(int), stream);
    bin_kernel<<<dim3(cdiv(NE, CHUNK), 2), 256, 0, stream>>>(dst, src, gbin, gbin_cnt);
    expand_kernel<<<dim3(NBIN, 2), 256, 0, stream>>>(gbin, gbin_cnt, cnt, ssrc);

    // h = x @ W_in + b_in
    gemm_mfma<<<dim3(GX, 1), 256, 0, stream>>>(xb, win_t, b_in, h, hb, N_NODES, 128, 128, 128, 0);

    for (int l = 0; l < NLAYER; l++) {
        gemm_mfma<<<dim3(GX, 3), 256, 0, stream>>>(hb, wqkv_t + l * 49152, bqkv + l * 384,
                                                   nullptr, qkvb, N_NODES, 128, 384, 128, 0);

        attn_fused<<<cdiv(N_NODES, 4), 256, 0, stream>>>(qkvb, cnt + l * N_NODES,
                                                         ssrc + (size_t)l * N_NODES * CAP, qkvb);

        gemm_ln<<<GL, 256, 0, stream>>>(qkvb, wo_t + l * 16384, bo + l * D,
                                        ln1g + l * D, ln1b + l * D, h, hb, 128, 384);

        gemm_mfma<<<dim3(GX, 2), 256, 0, stream>>>(hb, wf1_t + l * 32768, bf1 + l * FF,
                                                   nullptr, ffb, N_NODES, 128, 256, 128, 1);
        gemm_ln<<<GL, 256, 0, stream>>>(ffb, wf2_t + l * 32768, bf2 + l * D,
                                        ln2g + l * D, ln2b + l * D, h, hb, 256, 256);
    }

    predict_kernel<<<2 * PP, 64, 0, stream>>>(h, pos_src, pos_dst, neg_src, neg_dst,
                                              Wp1, bp1, Wp2, bp2, out);
}